// Round 8
// baseline (1154.912 us; speedup 1.0000x reference)
//
#include <hip/hip_runtime.h>
#include <hip/hip_bf16.h>

typedef unsigned short ushort_t;
typedef __attribute__((ext_vector_type(8))) short bf16x8;
typedef __attribute__((ext_vector_type(4))) float f32x4;

// Problem constants
#define NROWS 16384          // B*T
#define FDIM  512            // K
#define GE    640            // G*E
#define EDIM  320
#define DDIM  384
#define CB_OFF 12582912      // 16384*768
#define SCAL_OFF 23068672    // CB_OFF + 16384*640
// bf16 staging inside out[quantized region] (free until vq_rows)
#define XB_OFF 0
#define WB_OFF 4194304

#define LPITCH 324           // floats per LDS row (1296 B, 16B-aligned, bank-spread)

// ---------------- init accumulators ----------------
__global__ void vq_init_k(float* acc, int n) {
    int i = blockIdx.x * 256 + threadIdx.x;
    if (i < n) acc[i] = 0.0f;
}

// ---------------- fp32 -> bf16 convert (RNE) ----------------
static __device__ __forceinline__ unsigned f2bf(float f) {
    unsigned u = __float_as_uint(f);
    return (u + 0x7FFFu + ((u >> 16) & 1u)) >> 16;
}

__global__ __launch_bounds__(256) void convert_bf16_k(
    const float* __restrict__ X, const float* __restrict__ W,
    ushort_t* __restrict__ Xb, ushort_t* __restrict__ Wb)
{
    const size_t i = (size_t)blockIdx.x * 256 + threadIdx.x;
    const float4* src;
    ushort_t* dst;
    if (i < 1048576) {
        src = (const float4*)X + i * 2;
        dst = Xb + i * 8;
    } else {
        const size_t j = i - 1048576;
        src = (const float4*)W + j * 2;
        dst = Wb + j * 8;
    }
    const float4 v0 = src[0], v1 = src[1];
    uint4 o;
    o.x = f2bf(v0.x) | (f2bf(v0.y) << 16);
    o.y = f2bf(v0.z) | (f2bf(v0.w) << 16);
    o.z = f2bf(v1.x) | (f2bf(v1.y) << 16);
    o.w = f2bf(v1.z) | (f2bf(v1.w) << 16);
    *(uint4*)dst = o;
}

// ---------------- async global->LDS helper ----------------
static __device__ __forceinline__ void gload16(const void* g, void* l) {
    __builtin_amdgcn_global_load_lds(
        (const __attribute__((address_space(1))) unsigned int*)g,
        (__attribute__((address_space(3))) unsigned int*)l, 16, 0, 0);
}

// ---------------- MFMA GEMM: L = Xb @ Wb^T + b ----------------
__global__ __launch_bounds__(256) void gemm_mfma_k(
    const ushort_t* __restrict__ Xb, const ushort_t* __restrict__ Wb,
    const float* __restrict__ bias, float* __restrict__ L)
{
    __shared__ __align__(16) ushort_t As[128 * 32];
    __shared__ __align__(16) ushort_t Bs[128 * 32];

    const int tid  = threadIdx.x;
    const int lane = tid & 63;
    const int wv   = tid >> 6;
    const int wr   = (wv >> 1) * 64;
    const int wc   = (wv & 1) * 64;
    const int row0 = blockIdx.x * 128;
    const int col0 = blockIdx.y * 128;

    const int c0r = tid >> 2;
    const int c0k = (tid & 3) * 8;

    f32x4 acc[4][4] = {};

    const int rA = lane & 15;
    const int kb = (lane >> 4) * 8;

    for (int t = 0; t < 16; ++t) {
        const int k0 = t * 32;
        gload16(Xb + (size_t)(row0 + c0r) * FDIM + k0 + c0k,        &As[tid * 8]);
        gload16(Xb + (size_t)(row0 + 64 + c0r) * FDIM + k0 + c0k,   &As[2048 + tid * 8]);
        gload16(Wb + (size_t)(col0 + c0r) * FDIM + k0 + c0k,        &Bs[tid * 8]);
        gload16(Wb + (size_t)(col0 + 64 + c0r) * FDIM + k0 + c0k,   &Bs[2048 + tid * 8]);
        __syncthreads();

        bf16x8 af[4], bfr[4];
        #pragma unroll
        for (int mi = 0; mi < 4; ++mi)
            af[mi] = *(const bf16x8*)&As[(wr + mi * 16 + rA) * 32 + kb];
        #pragma unroll
        for (int ni = 0; ni < 4; ++ni)
            bfr[ni] = *(const bf16x8*)&Bs[(wc + ni * 16 + rA) * 32 + kb];

        #pragma unroll
        for (int mi = 0; mi < 4; ++mi)
            #pragma unroll
            for (int ni = 0; ni < 4; ++ni)
                acc[mi][ni] = __builtin_amdgcn_mfma_f32_16x16x32_bf16(
                    af[mi], bfr[ni], acc[mi][ni], 0, 0, 0);
        __syncthreads();
    }

    const int colb = col0 + wc + (lane & 15);
    const int rowb = row0 + wr + (lane >> 4) * 4;
    #pragma unroll
    for (int ni = 0; ni < 4; ++ni) {
        const int col = colb + ni * 16;
        const float bv = bias[col];
        #pragma unroll
        for (int mi = 0; mi < 4; ++mi) {
            const int row = rowb + mi * 16;
            #pragma unroll
            for (int j = 0; j < 4; ++j)
                L[(size_t)(row + j) * GE + col] = acc[mi][ni][j] + bv;
        }
    }
}

// ---------------- lane-per-row epilogue ----------------
// 4096 blocks x 64 threads. Block: 8 rows x one g. Lane = (r = tid&7, o = tid>>3);
// lane scans octant o (40 cols) of row r. Stage logits+gumbel to LDS coalesced,
// scan per-lane (conflict-free b128), merge max/sum across octants with 3 shfls.
// eh kept in registers -> logits read exactly once. Direct global fp32 atomics
// for the tiny (g,e) reductions.
__global__ __launch_bounds__(64) void vq_rows2_k(
    float* __restrict__ Lcb,                 // logits in, cb out (same region)
    const float* __restrict__ gumbel,
    const float* __restrict__ entries,
    float* __restrict__ out,                 // d_out base (quantized at 0)
    float* __restrict__ red_hard,            // ws[0..640)
    float* __restrict__ red_soft)            // ws[640..1280)
{
    __shared__ __align__(16) float lds_l[8][LPITCH];
    __shared__ __align__(16) float lds_g[8][LPITCH];
    __shared__ float yv_a[8];
    __shared__ int   gi_a[8];

    const int tid = threadIdx.x;
    const int r   = tid & 7;
    const int o   = tid >> 3;
    const int b   = blockIdx.x;          // 0..4095
    const int g   = b >> 11;             // 0/1
    const int n0  = (b & 2047) * 8;

    // ---- stage: 8 rows x 320 cols of logits and gumbel (coalesced f4) ----
    #pragma unroll
    for (int i = 0; i < 10; ++i) {
        const int idx = i * 64 + tid;          // 0..639 (f4 units)
        const int rr  = idx / 80;
        const int c4  = idx % 80;
        const f32x4 lv = *(const f32x4*)(Lcb + (size_t)(n0 + rr) * GE + g * EDIM + c4 * 4);
        *(f32x4*)&lds_l[rr][c4 * 4] = lv;
        const f32x4 gv = *(const f32x4*)(gumbel + ((size_t)(n0 + rr) * 2 + g) * EDIM + c4 * 4);
        *(f32x4*)&lds_g[rr][c4 * 4] = gv;
    }
    __syncthreads();

    // ---- P1: max + argmax (exact, first-index tie-break) ----
    float mh = -3.4e38f, mg = -3.4e38f;
    int hi = 0, gi = 0;
    #pragma unroll
    for (int s = 0; s < 10; ++s) {
        const f32x4 l4 = *(const f32x4*)&lds_l[r][o * 40 + s * 4];
        const f32x4 g4 = *(const f32x4*)&lds_g[r][o * 40 + s * 4];
        #pragma unroll
        for (int k = 0; k < 4; ++k) {
            const float lv = l4[k];
            const float tv = (lv + g4[k]) * 0.5f;   // (logits+gumbel)/TAU, TAU=2
            const int e = o * 40 + s * 4 + k;
            if (lv > mh) { mh = lv; hi = e; }
            if (tv > mg) { mg = tv; gi = e; }
        }
    }
    #pragma unroll
    for (int off = 8; off < 64; off <<= 1) {
        const float om = __shfl_xor(mh, off); const int oi = __shfl_xor(hi, off);
        if (om > mh || (om == mh && oi < hi)) { mh = om; hi = oi; }
        const float om2 = __shfl_xor(mg, off); const int oi2 = __shfl_xor(gi, off);
        if (om2 > mg || (om2 == mg && oi2 < gi)) { mg = om2; gi = oi2; }
    }

    // ---- P2: exp sums; keep eh in registers ----
    f32x4 eh[10];
    float sh = 0.f, sg = 0.f;
    #pragma unroll
    for (int s = 0; s < 10; ++s) {
        const f32x4 l4 = *(const f32x4*)&lds_l[r][o * 40 + s * 4];
        const f32x4 g4 = *(const f32x4*)&lds_g[r][o * 40 + s * 4];
        f32x4 e4;
        #pragma unroll
        for (int k = 0; k < 4; ++k) {
            const float lv = l4[k];
            const float tv = (lv + g4[k]) * 0.5f;
            const float ev = __expf(lv - mh);
            e4[k] = ev;
            sh += ev;
            sg += __expf(tv - mg);
        }
        eh[s] = e4;
    }
    #pragma unroll
    for (int off = 8; off < 64; off <<= 1) {
        sh += __shfl_xor(sh, off);
        sg += __shfl_xor(sg, off);
    }
    const float ish = 1.0f / sh;
    const float isg = 1.0f / sg;                 // y_soft at its argmax == 1/sg
    const float yv  = (1.0f - isg) + isg;        // straight-through value

    // ---- per-row scalars + hard-count atomics (8 lanes) ----
    if (o == 0) {
        yv_a[r] = yv;
        gi_a[r] = gi;
        atomicAdd(&red_hard[g * EDIM + hi], 1.0f);
    }
    __syncthreads();

    // ---- cb cooperative write (one-hot rows, coalesced f4) ----
    #pragma unroll
    for (int i = 0; i < 10; ++i) {
        const int idx = i * 64 + tid;
        const int rr  = idx / 80;
        const int c4  = idx % 80;
        const int gir = gi_a[rr];
        const float yvr = yv_a[rr];
        f32x4 cv;
        #pragma unroll
        for (int k = 0; k < 4; ++k)
            cv[k] = (c4 * 4 + k == gir) ? yvr : 0.0f;
        *(f32x4*)(Lcb + (size_t)(n0 + rr) * GE + g * EDIM + c4 * 4) = cv;
    }

    // ---- quantized cooperative write: yv * entries[g, gi, :] ----
    #pragma unroll
    for (int i = 0; i < 12; ++i) {
        const int idx = i * 64 + tid;          // 0..767 (f4 units)
        const int rr  = idx / 96;
        const int c4  = idx % 96;
        const int gir = gi_a[rr];
        const float yvr = yv_a[rr];
        const f32x4 ev = *(const f32x4*)(entries + ((size_t)(g * EDIM + gir)) * DDIM + c4 * 4);
        f32x4 qv;
        #pragma unroll
        for (int k = 0; k < 4; ++k) qv[k] = yvr * ev[k];
        *(f32x4*)(out + (size_t)(n0 + rr) * 768 + g * DDIM + c4 * 4) = qv;
    }

    // ---- P3: soft probs from registers; reduce 8 rows via 3 shfls; atomics ----
    #pragma unroll
    for (int s = 0; s < 10; ++s) {
        f32x4 p4;
        #pragma unroll
        for (int k = 0; k < 4; ++k) p4[k] = eh[s][k] * ish;
        #pragma unroll
        for (int off = 1; off < 8; off <<= 1) {
            #pragma unroll
            for (int k = 0; k < 4; ++k) p4[k] += __shfl_xor(p4[k], off);
        }
        if (r == 0) {
            #pragma unroll
            for (int k = 0; k < 4; ++k)
                atomicAdd(&red_soft[g * EDIM + o * 40 + s * 4 + k], p4[k]);
        }
    }
}

// ---------------- perplexities ----------------
__global__ void vq_final_k(const float* __restrict__ red_hard,
                           const float* __restrict__ red_soft,
                           float* __restrict__ out)
{
    const int lane = threadIdx.x & 63;
    float code = 0.f, prob = 0.f;
    for (int g = 0; g < 2; ++g) {
        float shh = 0.f, sss = 0.f;
        #pragma unroll
        for (int j = 0; j < 5; ++j) {
            const int e = g * EDIM + lane + j * 64;
            const float ph = red_hard[e] * (1.0f / 16384.0f);
            const float ps = red_soft[e] * (1.0f / 16384.0f);
            shh += ph * __logf(ph + 1e-7f);
            sss += ps * __logf(ps + 1e-7f);
        }
        #pragma unroll
        for (int off = 32; off > 0; off >>= 1) {
            shh += __shfl_xor(shh, off);
            sss += __shfl_xor(sss, off);
        }
        code += __expf(-shh);
        prob += __expf(-sss);
    }
    if (threadIdx.x == 0) {
        out[SCAL_OFF + 0] = code;
        out[SCAL_OFF + 1] = prob;
    }
}

extern "C" void kernel_launch(void* const* d_in, const int* in_sizes, int n_in,
                              void* d_out, int out_size, void* d_ws, size_t ws_size,
                              hipStream_t stream) {
    const float* x       = (const float*)d_in[0];
    const float* proj_w  = (const float*)d_in[1];
    const float* proj_b  = (const float*)d_in[2];
    const float* entries = (const float*)d_in[3];
    const float* gumbel  = (const float*)d_in[4];
    float* out = (float*)d_out;
    float* ws  = (float*)d_ws;
    float* logits = out + CB_OFF;
    ushort_t* Xb = (ushort_t*)(out + XB_OFF);
    ushort_t* Wb = (ushort_t*)(out + WB_OFF);

    float* red_hard = ws;            // 640 floats
    float* red_soft = ws + 640;      // 640 floats

    hipLaunchKernelGGL(vq_init_k, dim3(5), dim3(256), 0, stream, ws, 1280);
    hipLaunchKernelGGL(convert_bf16_k, dim3(4256), dim3(256), 0, stream,
                       x, proj_w, Xb, Wb);
    hipLaunchKernelGGL(gemm_mfma_k, dim3(NROWS / 128, GE / 128), dim3(256), 0, stream,
                       Xb, Wb, proj_b, logits);
    hipLaunchKernelGGL(vq_rows2_k, dim3(4096), dim3(64), 0, stream,
                       logits, gumbel, entries, out, red_hard, red_soft);
    hipLaunchKernelGGL(vq_final_k, dim3(1), dim3(64), 0, stream,
                       red_hard, red_soft, out);
}

// Round 9
// 253.199 us; speedup vs baseline: 4.5613x; 4.5613x over previous
//
#include <hip/hip_runtime.h>
#include <hip/hip_bf16.h>

typedef unsigned short ushort_t;
typedef __attribute__((ext_vector_type(8))) short bf16x8;
typedef __attribute__((ext_vector_type(4))) float f32x4;

// Problem constants
#define NROWS 16384          // B*T
#define FDIM  512            // K
#define GE    640            // G*E
#define EDIM  320
#define DDIM  384
#define CB_OFF 12582912      // 16384*768
#define SCAL_OFF 23068672    // CB_OFF + 16384*640
// bf16 staging inside out[quantized region] (free until vq_rows)
#define XB_OFF 0
#define WB_OFF 4194304

#define LPITCH 324           // floats per LDS row; quad-bank balanced for scan

// ws layout (floats): [0,640) red_hard | [640,1280) red_soft | [1280,...) slots
#define WS_SLOT_OFF 1280
#define SLOT_BIG_ROWS 2048   // plain-store path: 2048 rows x 640 floats = 5.24 MB
#define SLOT_SMALL_COPIES 32 // atomic path: 32 copies x 640 floats

// ---------------- init accumulators ----------------
__global__ void vq_init_k(float* acc, int n) {
    int i = blockIdx.x * 256 + threadIdx.x;
    if (i < n) acc[i] = 0.0f;
}

// ---------------- fp32 -> bf16 convert (RNE) ----------------
static __device__ __forceinline__ unsigned f2bf(float f) {
    unsigned u = __float_as_uint(f);
    return (u + 0x7FFFu + ((u >> 16) & 1u)) >> 16;
}

__global__ __launch_bounds__(256) void convert_bf16_k(
    const float* __restrict__ X, const float* __restrict__ W,
    ushort_t* __restrict__ Xb, ushort_t* __restrict__ Wb)
{
    const size_t i = (size_t)blockIdx.x * 256 + threadIdx.x;
    const float4* src;
    ushort_t* dst;
    if (i < 1048576) {
        src = (const float4*)X + i * 2;
        dst = Xb + i * 8;
    } else {
        const size_t j = i - 1048576;
        src = (const float4*)W + j * 2;
        dst = Wb + j * 8;
    }
    const float4 v0 = src[0], v1 = src[1];
    uint4 o;
    o.x = f2bf(v0.x) | (f2bf(v0.y) << 16);
    o.y = f2bf(v0.z) | (f2bf(v0.w) << 16);
    o.z = f2bf(v1.x) | (f2bf(v1.y) << 16);
    o.w = f2bf(v1.z) | (f2bf(v1.w) << 16);
    *(uint4*)dst = o;
}

// ---------------- async global->LDS helper ----------------
static __device__ __forceinline__ void gload16(const void* g, void* l) {
    __builtin_amdgcn_global_load_lds(
        (const __attribute__((address_space(1))) unsigned int*)g,
        (__attribute__((address_space(3))) unsigned int*)l, 16, 0, 0);
}

// ---------------- MFMA GEMM: L = Xb @ Wb^T + b ----------------
__global__ __launch_bounds__(256) void gemm_mfma_k(
    const ushort_t* __restrict__ Xb, const ushort_t* __restrict__ Wb,
    const float* __restrict__ bias, float* __restrict__ L)
{
    __shared__ __align__(16) ushort_t As[128 * 32];
    __shared__ __align__(16) ushort_t Bs[128 * 32];

    const int tid  = threadIdx.x;
    const int lane = tid & 63;
    const int wv   = tid >> 6;
    const int wr   = (wv >> 1) * 64;
    const int wc   = (wv & 1) * 64;
    const int row0 = blockIdx.x * 128;
    const int col0 = blockIdx.y * 128;

    const int c0r = tid >> 2;
    const int c0k = (tid & 3) * 8;

    f32x4 acc[4][4] = {};

    const int rA = lane & 15;
    const int kb = (lane >> 4) * 8;

    for (int t = 0; t < 16; ++t) {
        const int k0 = t * 32;
        gload16(Xb + (size_t)(row0 + c0r) * FDIM + k0 + c0k,        &As[tid * 8]);
        gload16(Xb + (size_t)(row0 + 64 + c0r) * FDIM + k0 + c0k,   &As[2048 + tid * 8]);
        gload16(Wb + (size_t)(col0 + c0r) * FDIM + k0 + c0k,        &Bs[tid * 8]);
        gload16(Wb + (size_t)(col0 + 64 + c0r) * FDIM + k0 + c0k,   &Bs[2048 + tid * 8]);
        __syncthreads();

        bf16x8 af[4], bfr[4];
        #pragma unroll
        for (int mi = 0; mi < 4; ++mi)
            af[mi] = *(const bf16x8*)&As[(wr + mi * 16 + rA) * 32 + kb];
        #pragma unroll
        for (int ni = 0; ni < 4; ++ni)
            bfr[ni] = *(const bf16x8*)&Bs[(wc + ni * 16 + rA) * 32 + kb];

        #pragma unroll
        for (int mi = 0; mi < 4; ++mi)
            #pragma unroll
            for (int ni = 0; ni < 4; ++ni)
                acc[mi][ni] = __builtin_amdgcn_mfma_f32_16x16x32_bf16(
                    af[mi], bfr[ni], acc[mi][ni], 0, 0, 0);
        __syncthreads();
    }

    const int colb = col0 + wc + (lane & 15);
    const int rowb = row0 + wr + (lane >> 4) * 4;
    #pragma unroll
    for (int ni = 0; ni < 4; ++ni) {
        const int col = colb + ni * 16;
        const float bv = bias[col];
        #pragma unroll
        for (int mi = 0; mi < 4; ++mi) {
            const int row = rowb + mi * 16;
            #pragma unroll
            for (int j = 0; j < 4; ++j)
                L[(size_t)(row + j) * GE + col] = acc[mi][ni][j] + bv;
        }
    }
}

// ---------------- lane-per-row epilogue ----------------
// 4096 blocks x 64 threads, 8 rows/block. r = tid&7 (row), o = tid>>3 (octant).
// Soft-prob partials leave the block as ONE coalesced 320-float plain store
// per block into a private slot row (mode 1) or 32-copy privatized atomics
// (mode 0). NEVER high-contention direct atomics (R8: 1170 us lesson).
__global__ __launch_bounds__(64) void vq_rows2_k(
    float* __restrict__ Lcb,                 // logits in, cb out (same region)
    const float* __restrict__ gumbel,
    const float* __restrict__ entries,
    float* __restrict__ out,                 // d_out base (quantized at 0)
    float* __restrict__ red_hard,            // ws[0..640)
    float* __restrict__ slotS,               // ws[1280..) slot rows / copies
    int mode)                                // 1 = plain slots, 0 = atomic copies
{
    __shared__ __align__(16) float lds_l[8][LPITCH];
    __shared__ __align__(16) float lds_g[8][LPITCH];
    __shared__ float part[320];
    __shared__ float yv_a[8];
    __shared__ int   gi_a[8];

    const int tid = threadIdx.x;
    const int r   = tid & 7;
    const int o   = tid >> 3;
    const int b   = blockIdx.x;          // 0..4095
    const int g   = b >> 11;             // 0/1
    const int n0  = (b & 2047) * 8;

    // ---- stage: 8 rows x 320 cols of logits and gumbel (coalesced f4) ----
    #pragma unroll
    for (int i = 0; i < 10; ++i) {
        const int idx = i * 64 + tid;          // 0..639 (f4 units)
        const int rr  = idx / 80;
        const int c4  = idx % 80;
        const f32x4 lv = *(const f32x4*)(Lcb + (size_t)(n0 + rr) * GE + g * EDIM + c4 * 4);
        *(f32x4*)&lds_l[rr][c4 * 4] = lv;
        const f32x4 gv = *(const f32x4*)(gumbel + ((size_t)(n0 + rr) * 2 + g) * EDIM + c4 * 4);
        *(f32x4*)&lds_g[rr][c4 * 4] = gv;
    }
    __syncthreads();

    // ---- P1: max + argmax (exact, first-index tie-break) ----
    float mh = -3.4e38f, mg = -3.4e38f;
    int hi = 0, gi = 0;
    #pragma unroll
    for (int s = 0; s < 10; ++s) {
        const f32x4 l4 = *(const f32x4*)&lds_l[r][o * 40 + s * 4];
        const f32x4 g4 = *(const f32x4*)&lds_g[r][o * 40 + s * 4];
        #pragma unroll
        for (int k = 0; k < 4; ++k) {
            const float lv = l4[k];
            const float tv = (lv + g4[k]) * 0.5f;   // (logits+gumbel)/TAU, TAU=2
            const int e = o * 40 + s * 4 + k;
            if (lv > mh) { mh = lv; hi = e; }
            if (tv > mg) { mg = tv; gi = e; }
        }
    }
    #pragma unroll
    for (int off = 8; off < 64; off <<= 1) {
        const float om = __shfl_xor(mh, off); const int oi = __shfl_xor(hi, off);
        if (om > mh || (om == mh && oi < hi)) { mh = om; hi = oi; }
        const float om2 = __shfl_xor(mg, off); const int oi2 = __shfl_xor(gi, off);
        if (om2 > mg || (om2 == mg && oi2 < gi)) { mg = om2; gi = oi2; }
    }

    // ---- P2: exp sums; keep eh in registers ----
    f32x4 eh[10];
    float sh = 0.f, sg = 0.f;
    #pragma unroll
    for (int s = 0; s < 10; ++s) {
        const f32x4 l4 = *(const f32x4*)&lds_l[r][o * 40 + s * 4];
        const f32x4 g4 = *(const f32x4*)&lds_g[r][o * 40 + s * 4];
        f32x4 e4;
        #pragma unroll
        for (int k = 0; k < 4; ++k) {
            const float lv = l4[k];
            const float tv = (lv + g4[k]) * 0.5f;
            const float ev = __expf(lv - mh);
            e4[k] = ev;
            sh += ev;
            sg += __expf(tv - mg);
        }
        eh[s] = e4;
    }
    #pragma unroll
    for (int off = 8; off < 64; off <<= 1) {
        sh += __shfl_xor(sh, off);
        sg += __shfl_xor(sg, off);
    }
    const float ish = 1.0f / sh;
    const float isg = 1.0f / sg;                 // y_soft at its argmax == 1/sg
    const float yv  = (1.0f - isg) + isg;        // straight-through value

    // ---- per-row scalars + hard-count atomics (8 lanes, ~100 RMW/addr) ----
    if (o == 0) {
        yv_a[r] = yv;
        gi_a[r] = gi;
        atomicAdd(&red_hard[g * EDIM + hi], 1.0f);
    }
    __syncthreads();

    // ---- cb cooperative write (one-hot rows, coalesced f4) ----
    #pragma unroll
    for (int i = 0; i < 10; ++i) {
        const int idx = i * 64 + tid;
        const int rr  = idx / 80;
        const int c4  = idx % 80;
        const int gir = gi_a[rr];
        const float yvr = yv_a[rr];
        f32x4 cv;
        #pragma unroll
        for (int k = 0; k < 4; ++k)
            cv[k] = (c4 * 4 + k == gir) ? yvr : 0.0f;
        *(f32x4*)(Lcb + (size_t)(n0 + rr) * GE + g * EDIM + c4 * 4) = cv;
    }

    // ---- quantized cooperative write: yv * entries[g, gi, :] ----
    #pragma unroll
    for (int i = 0; i < 12; ++i) {
        const int idx = i * 64 + tid;          // 0..767 (f4 units)
        const int rr  = idx / 96;
        const int c4  = idx % 96;
        const int gir = gi_a[rr];
        const float yvr = yv_a[rr];
        const f32x4 ev = *(const f32x4*)(entries + ((size_t)(g * EDIM + gir)) * DDIM + c4 * 4);
        f32x4 qv;
        #pragma unroll
        for (int k = 0; k < 4; ++k) qv[k] = yvr * ev[k];
        *(f32x4*)(out + (size_t)(n0 + rr) * 768 + g * DDIM + c4 * 4) = qv;
    }

    // ---- P3: block-level soft partial -> LDS, then low-contention sink ----
    #pragma unroll
    for (int s = 0; s < 10; ++s) {
        f32x4 p4;
        #pragma unroll
        for (int k = 0; k < 4; ++k) p4[k] = eh[s][k] * ish;
        #pragma unroll
        for (int off = 1; off < 8; off <<= 1) {
            #pragma unroll
            for (int k = 0; k < 4; ++k) p4[k] += __shfl_xor(p4[k], off);
        }
        if (r == 0) *(f32x4*)&part[o * 40 + s * 4] = p4;
    }
    __syncthreads();

    if (mode == 1) {
        // private slot row, plain coalesced stores (no atomics at all)
        float* srow = slotS + (size_t)(b & 2047) * 640 + g * EDIM;
        #pragma unroll
        for (int k = 0; k < 5; ++k)
            srow[tid + k * 64] = part[tid + k * 64];
    } else {
        // 32-copy privatized atomics (~64 RMW/addr)
        float* crow = slotS + (size_t)(b & (SLOT_SMALL_COPIES - 1)) * 640 + g * EDIM;
        #pragma unroll
        for (int k = 0; k < 5; ++k)
            atomicAdd(&crow[tid + k * 64], part[tid + k * 64]);
    }
}

// ---------------- slot reduction: red_soft[idx] = sum over rows ----------------
__global__ __launch_bounds__(64) void reduce_soft2_k(
    const float* __restrict__ slotS, int nrows, float* __restrict__ red_soft)
{
    const int idx = blockIdx.x * 64 + threadIdx.x;   // 0..639
    if (idx >= 640) return;
    float a0 = 0.f, a1 = 0.f, a2 = 0.f, a3 = 0.f;
    int k = 0;
    for (; k + 4 <= nrows; k += 4) {
        a0 += slotS[(size_t)(k + 0) * 640 + idx];
        a1 += slotS[(size_t)(k + 1) * 640 + idx];
        a2 += slotS[(size_t)(k + 2) * 640 + idx];
        a3 += slotS[(size_t)(k + 3) * 640 + idx];
    }
    for (; k < nrows; ++k) a0 += slotS[(size_t)k * 640 + idx];
    red_soft[idx] = (a0 + a1) + (a2 + a3);
}

// ---------------- perplexities ----------------
__global__ void vq_final_k(const float* __restrict__ red_hard,
                           const float* __restrict__ red_soft,
                           float* __restrict__ out)
{
    const int lane = threadIdx.x & 63;
    float code = 0.f, prob = 0.f;
    for (int g = 0; g < 2; ++g) {
        float shh = 0.f, sss = 0.f;
        #pragma unroll
        for (int j = 0; j < 5; ++j) {
            const int e = g * EDIM + lane + j * 64;
            const float ph = red_hard[e] * (1.0f / 16384.0f);
            const float ps = red_soft[e] * (1.0f / 16384.0f);
            shh += ph * __logf(ph + 1e-7f);
            sss += ps * __logf(ps + 1e-7f);
        }
        #pragma unroll
        for (int off = 32; off > 0; off >>= 1) {
            shh += __shfl_xor(shh, off);
            sss += __shfl_xor(sss, off);
        }
        code += __expf(-shh);
        prob += __expf(-sss);
    }
    if (threadIdx.x == 0) {
        out[SCAL_OFF + 0] = code;
        out[SCAL_OFF + 1] = prob;
    }
}

extern "C" void kernel_launch(void* const* d_in, const int* in_sizes, int n_in,
                              void* d_out, int out_size, void* d_ws, size_t ws_size,
                              hipStream_t stream) {
    const float* x       = (const float*)d_in[0];
    const float* proj_w  = (const float*)d_in[1];
    const float* proj_b  = (const float*)d_in[2];
    const float* entries = (const float*)d_in[3];
    const float* gumbel  = (const float*)d_in[4];
    float* out = (float*)d_out;
    float* ws  = (float*)d_ws;
    float* logits = out + CB_OFF;
    ushort_t* Xb = (ushort_t*)(out + XB_OFF);
    ushort_t* Wb = (ushort_t*)(out + WB_OFF);

    float* red_hard = ws;            // 640 floats
    float* red_soft = ws + 640;      // 640 floats
    float* slotS    = ws + WS_SLOT_OFF;

    const int mode = (ws_size >= (size_t)(WS_SLOT_OFF + SLOT_BIG_ROWS * 640) * 4)
                         ? 1 : 0;
    const int nrows = (mode == 1) ? SLOT_BIG_ROWS : SLOT_SMALL_COPIES;
    // plain-slot rows are fully overwritten each call; copies must be zeroed
    const int nz = (mode == 1) ? 1280 : (1280 + SLOT_SMALL_COPIES * 640);

    hipLaunchKernelGGL(vq_init_k, dim3((nz + 255) / 256), dim3(256), 0, stream,
                       ws, nz);
    hipLaunchKernelGGL(convert_bf16_k, dim3(4256), dim3(256), 0, stream,
                       x, proj_w, Xb, Wb);
    hipLaunchKernelGGL(gemm_mfma_k, dim3(NROWS / 128, GE / 128), dim3(256), 0, stream,
                       Xb, Wb, proj_b, logits);
    hipLaunchKernelGGL(vq_rows2_k, dim3(4096), dim3(64), 0, stream,
                       logits, gumbel, entries, out, red_hard, slotS, mode);
    hipLaunchKernelGGL(reduce_soft2_k, dim3(10), dim3(64), 0, stream,
                       slotS, nrows, red_soft);
    hipLaunchKernelGGL(vq_final_k, dim3(1), dim3(64), 0, stream,
                       red_hard, red_soft, out);
}

// Round 10
// 104.664 us; speedup vs baseline: 11.0345x; 2.4192x over previous
//
#include <hip/hip_runtime.h>
#include <hip/hip_bf16.h>

typedef unsigned short ushort_t;
typedef __attribute__((ext_vector_type(8))) short bf16x8;
typedef __attribute__((ext_vector_type(4))) float f32x4;

// Problem constants
#define NROWS 16384          // B*T
#define FDIM  512            // K
#define GE    640            // G*E
#define EDIM  320
#define DDIM  384
#define CB_OFF 12582912      // 16384*768
#define SCAL_OFF 23068672    // CB_OFF + 16384*640
// bf16 staging inside out[quantized region] (dead after gemm, before emit)
#define XB_OFF 0
#define WB_OFF 4194304

#define LPITCH 324           // floats per LDS row; quad-bank balanced for scan

// ws layout (floats): [0,640) red_hard | [640,1280) red_soft |
//                     [1280, 1280+65536) giyv (32768 float2) | [66816, ...) slots
#define GIYV_OFF 1280
#define SLOT_OFF (1280 + 65536)
#define SLOT_BIG_ROWS 2048   // plain-store path: 2048 rows x 640 floats
#define SLOT_SMALL_COPIES 64 // atomic fallback: 64 copies x 640 floats

// ---------------- init accumulators ----------------
__global__ void vq_init_k(float* acc, int n) {
    int i = blockIdx.x * 256 + threadIdx.x;
    if (i < n) acc[i] = 0.0f;
}

// ---------------- fp32 -> bf16 convert (RNE) ----------------
static __device__ __forceinline__ unsigned f2bf(float f) {
    unsigned u = __float_as_uint(f);
    return (u + 0x7FFFu + ((u >> 16) & 1u)) >> 16;
}

__global__ __launch_bounds__(256) void convert_bf16_k(
    const float* __restrict__ X, const float* __restrict__ W,
    ushort_t* __restrict__ Xb, ushort_t* __restrict__ Wb)
{
    const size_t i = (size_t)blockIdx.x * 256 + threadIdx.x;
    const float4* src;
    ushort_t* dst;
    if (i < 1048576) {
        src = (const float4*)X + i * 2;
        dst = Xb + i * 8;
    } else {
        const size_t j = i - 1048576;
        src = (const float4*)W + j * 2;
        dst = Wb + j * 8;
    }
    const float4 v0 = src[0], v1 = src[1];
    uint4 o;
    o.x = f2bf(v0.x) | (f2bf(v0.y) << 16);
    o.y = f2bf(v0.z) | (f2bf(v0.w) << 16);
    o.z = f2bf(v1.x) | (f2bf(v1.y) << 16);
    o.w = f2bf(v1.z) | (f2bf(v1.w) << 16);
    *(uint4*)dst = o;
}

// ---------------- async global->LDS helper ----------------
static __device__ __forceinline__ void gload16(const void* g, void* l) {
    __builtin_amdgcn_global_load_lds(
        (const __attribute__((address_space(1))) unsigned int*)g,
        (__attribute__((address_space(3))) unsigned int*)l, 16, 0, 0);
}

// ---------------- MFMA GEMM: L = Xb @ Wb^T + b ----------------
__global__ __launch_bounds__(256) void gemm_mfma_k(
    const ushort_t* __restrict__ Xb, const ushort_t* __restrict__ Wb,
    const float* __restrict__ bias, float* __restrict__ L)
{
    __shared__ __align__(16) ushort_t As[128 * 32];
    __shared__ __align__(16) ushort_t Bs[128 * 32];

    const int tid  = threadIdx.x;
    const int lane = tid & 63;
    const int wv   = tid >> 6;
    const int wr   = (wv >> 1) * 64;
    const int wc   = (wv & 1) * 64;
    const int row0 = blockIdx.x * 128;
    const int col0 = blockIdx.y * 128;

    const int c0r = tid >> 2;
    const int c0k = (tid & 3) * 8;

    f32x4 acc[4][4] = {};

    const int rA = lane & 15;
    const int kb = (lane >> 4) * 8;

    for (int t = 0; t < 16; ++t) {
        const int k0 = t * 32;
        gload16(Xb + (size_t)(row0 + c0r) * FDIM + k0 + c0k,        &As[tid * 8]);
        gload16(Xb + (size_t)(row0 + 64 + c0r) * FDIM + k0 + c0k,   &As[2048 + tid * 8]);
        gload16(Wb + (size_t)(col0 + c0r) * FDIM + k0 + c0k,        &Bs[tid * 8]);
        gload16(Wb + (size_t)(col0 + 64 + c0r) * FDIM + k0 + c0k,   &Bs[2048 + tid * 8]);
        __syncthreads();

        bf16x8 af[4], bfr[4];
        #pragma unroll
        for (int mi = 0; mi < 4; ++mi)
            af[mi] = *(const bf16x8*)&As[(wr + mi * 16 + rA) * 32 + kb];
        #pragma unroll
        for (int ni = 0; ni < 4; ++ni)
            bfr[ni] = *(const bf16x8*)&Bs[(wc + ni * 16 + rA) * 32 + kb];

        #pragma unroll
        for (int mi = 0; mi < 4; ++mi)
            #pragma unroll
            for (int ni = 0; ni < 4; ++ni)
                acc[mi][ni] = __builtin_amdgcn_mfma_f32_16x16x32_bf16(
                    af[mi], bfr[ni], acc[mi][ni], 0, 0, 0);
        __syncthreads();
    }

    const int colb = col0 + wc + (lane & 15);
    const int rowb = row0 + wr + (lane >> 4) * 4;
    #pragma unroll
    for (int ni = 0; ni < 4; ++ni) {
        const int col = colb + ni * 16;
        const float bv = bias[col];
        #pragma unroll
        for (int mi = 0; mi < 4; ++mi) {
            const int row = rowb + mi * 16;
            #pragma unroll
            for (int j = 0; j < 4; ++j)
                L[(size_t)(row + j) * GE + col] = acc[mi][ni][j] + bv;
        }
    }
}

// ---------------- SCAN: per-(n,g) stats only, no output streams ----------------
// 4096 blocks x 64 threads, 8 rows/block. r = tid&7 (row), o = tid>>3 (octant).
// Outputs: giyv[(n*2+g)] = (gi, yv); soft partials -> slots (plain stores) or
// 64-copy atomics; hard counts -> direct atomics (32K ops, ~51/addr).
__global__ __launch_bounds__(64) void vq_scan_k(
    const float* __restrict__ Lcb,           // logits (cb region, read-only here)
    const float* __restrict__ gumbel,
    float* __restrict__ red_hard,            // ws[0..640)
    float* __restrict__ giyv,                // ws[GIYV_OFF..), 32768 float2
    float* __restrict__ slotS,               // ws[SLOT_OFF..)
    int mode)                                // 1 = plain slots, 0 = atomic copies
{
    __shared__ __align__(16) float lds_l[8][LPITCH];
    __shared__ __align__(16) float lds_g[8][LPITCH];
    __shared__ float part[320];

    const int tid = threadIdx.x;
    const int r   = tid & 7;
    const int o   = tid >> 3;
    const int b   = blockIdx.x;          // 0..4095
    const int g   = b >> 11;             // 0/1
    const int n0  = (b & 2047) * 8;

    // ---- stage: 8 rows x 320 cols of logits and gumbel (coalesced f4) ----
    #pragma unroll
    for (int i = 0; i < 10; ++i) {
        const int idx = i * 64 + tid;          // 0..639 (f4 units)
        const int rr  = idx / 80;
        const int c4  = idx % 80;
        const f32x4 lv = *(const f32x4*)(Lcb + (size_t)(n0 + rr) * GE + g * EDIM + c4 * 4);
        *(f32x4*)&lds_l[rr][c4 * 4] = lv;
        const f32x4 gv = *(const f32x4*)(gumbel + ((size_t)(n0 + rr) * 2 + g) * EDIM + c4 * 4);
        *(f32x4*)&lds_g[rr][c4 * 4] = gv;
    }
    __syncthreads();

    // ---- P1: max + argmax (exact, first-index tie-break) ----
    float mh = -3.4e38f, mg = -3.4e38f;
    int hi = 0, gi = 0;
    #pragma unroll
    for (int s = 0; s < 10; ++s) {
        const f32x4 l4 = *(const f32x4*)&lds_l[r][o * 40 + s * 4];
        const f32x4 g4 = *(const f32x4*)&lds_g[r][o * 40 + s * 4];
        #pragma unroll
        for (int k = 0; k < 4; ++k) {
            const float lv = l4[k];
            const float tv = (lv + g4[k]) * 0.5f;   // (logits+gumbel)/TAU, TAU=2
            const int e = o * 40 + s * 4 + k;
            if (lv > mh) { mh = lv; hi = e; }
            if (tv > mg) { mg = tv; gi = e; }
        }
    }
    #pragma unroll
    for (int off = 8; off < 64; off <<= 1) {
        const float om = __shfl_xor(mh, off); const int oi = __shfl_xor(hi, off);
        if (om > mh || (om == mh && oi < hi)) { mh = om; hi = oi; }
        const float om2 = __shfl_xor(mg, off); const int oi2 = __shfl_xor(gi, off);
        if (om2 > mg || (om2 == mg && oi2 < gi)) { mg = om2; gi = oi2; }
    }

    // ---- P2: exp sums; keep eh in registers ----
    f32x4 eh[10];
    float sh = 0.f, sg = 0.f;
    #pragma unroll
    for (int s = 0; s < 10; ++s) {
        const f32x4 l4 = *(const f32x4*)&lds_l[r][o * 40 + s * 4];
        const f32x4 g4 = *(const f32x4*)&lds_g[r][o * 40 + s * 4];
        f32x4 e4;
        #pragma unroll
        for (int k = 0; k < 4; ++k) {
            const float lv = l4[k];
            const float tv = (lv + g4[k]) * 0.5f;
            const float ev = __expf(lv - mh);
            e4[k] = ev;
            sh += ev;
            sg += __expf(tv - mg);
        }
        eh[s] = e4;
    }
    #pragma unroll
    for (int off = 8; off < 64; off <<= 1) {
        sh += __shfl_xor(sh, off);
        sg += __shfl_xor(sg, off);
    }
    const float ish = 1.0f / sh;
    const float isg = 1.0f / sg;                 // y_soft at its argmax == 1/sg
    const float yv  = (1.0f - isg) + isg;        // straight-through value

    // ---- per-row outputs: giyv + hard-count atomic (8 lanes/block) ----
    if (o == 0) {
        ((float2*)giyv)[(size_t)(n0 + r) * 2 + g] =
            make_float2(__int_as_float(gi), yv);
        atomicAdd(&red_hard[g * EDIM + hi], 1.0f);
    }

    // ---- P3: block soft partial -> LDS part[], then low-contention sink ----
    #pragma unroll
    for (int s = 0; s < 10; ++s) {
        f32x4 p4;
        #pragma unroll
        for (int k = 0; k < 4; ++k) p4[k] = eh[s][k] * ish;
        #pragma unroll
        for (int off = 1; off < 8; off <<= 1) {
            #pragma unroll
            for (int k = 0; k < 4; ++k) p4[k] += __shfl_xor(p4[k], off);
        }
        if (r == 0) *(f32x4*)&part[o * 40 + s * 4] = p4;
    }
    __syncthreads();

    if (mode == 1) {
        float* srow = slotS + (size_t)(b & 2047) * 640 + g * EDIM;
        #pragma unroll
        for (int k = 0; k < 5; ++k)
            srow[tid + k * 64] = part[tid + k * 64];
    } else {
        float* crow = slotS + (size_t)(b & (SLOT_SMALL_COPIES - 1)) * 640 + g * EDIM;
        #pragma unroll
        for (int k = 0; k < 5; ++k)
            atomicAdd(&crow[tid + k * 64], part[tid + k * 64]);
    }
}

// ---------------- EMIT: cb one-hot + quantized, pure coalesced streams ----------------
// 2048 blocks x 256 threads; block bb owns rows n0..n0+7 (both g).
__global__ __launch_bounds__(256) void vq_emit_k(
    const float* __restrict__ giyv,
    const float* __restrict__ entries,
    float* __restrict__ cb,                  // logits region, overwritten
    float* __restrict__ qout)                // d_out base
{
    const int tid = threadIdx.x;
    const int n0  = blockIdx.x * 8;

    // cb: 8 rows x 640 = 1280 f4
    #pragma unroll
    for (int it = 0; it < 5; ++it) {
        const int idx = it * 256 + tid;        // 0..1279
        const int rr  = idx / 160;
        const int c4  = idx % 160;
        const int g   = (c4 >= 80) ? 1 : 0;
        const int e4  = (c4 - g * 80) * 4;
        const float2 f2 = ((const float2*)giyv)[(size_t)(n0 + rr) * 2 + g];
        const int   gi = __float_as_int(f2.x);
        const float yv = f2.y;
        f32x4 cv;
        #pragma unroll
        for (int k = 0; k < 4; ++k) cv[k] = (e4 + k == gi) ? yv : 0.0f;
        *(f32x4*)(cb + (size_t)(n0 + rr) * GE + c4 * 4) = cv;
    }

    // quantized: 8 rows x 768 = 1536 f4
    #pragma unroll
    for (int it = 0; it < 6; ++it) {
        const int idx = it * 256 + tid;        // 0..1535
        const int rr  = idx / 192;
        const int c4  = idx % 192;
        const int g   = (c4 >= 96) ? 1 : 0;
        const int d4  = (c4 - g * 96) * 4;
        const float2 f2 = ((const float2*)giyv)[(size_t)(n0 + rr) * 2 + g];
        const int   gi = __float_as_int(f2.x);
        const float yv = f2.y;
        const f32x4 ev = *(const f32x4*)(entries + ((size_t)(g * EDIM + gi)) * DDIM + d4);
        f32x4 qv;
        #pragma unroll
        for (int k = 0; k < 4; ++k) qv[k] = yv * ev[k];
        *(f32x4*)(qout + (size_t)(n0 + rr) * 768 + c4 * 4) = qv;
    }
}

// ---------------- slot reduction, parallel: thread = (chunk, col) ----------------
__global__ __launch_bounds__(256) void reduce_soft3_k(
    const float* __restrict__ slotS, int nrows, float* __restrict__ red_soft)
{
    const int gid = blockIdx.x * 256 + threadIdx.x;
    const int nchunk = nrows / 32;
    if (gid >= 640 * nchunk) return;
    const int col   = gid % 640;
    const int chunk = gid / 640;
    const int base  = chunk * 32;
    float a0 = 0.f, a1 = 0.f, a2 = 0.f, a3 = 0.f;
    #pragma unroll
    for (int k = 0; k < 32; k += 4) {
        a0 += slotS[(size_t)(base + k + 0) * 640 + col];
        a1 += slotS[(size_t)(base + k + 1) * 640 + col];
        a2 += slotS[(size_t)(base + k + 2) * 640 + col];
        a3 += slotS[(size_t)(base + k + 3) * 640 + col];
    }
    atomicAdd(&red_soft[col], (a0 + a1) + (a2 + a3));   // <=64 RMW per address
}

// ---------------- perplexities ----------------
__global__ void vq_final_k(const float* __restrict__ red_hard,
                           const float* __restrict__ red_soft,
                           float* __restrict__ out)
{
    const int lane = threadIdx.x & 63;
    float code = 0.f, prob = 0.f;
    for (int g = 0; g < 2; ++g) {
        float shh = 0.f, sss = 0.f;
        #pragma unroll
        for (int j = 0; j < 5; ++j) {
            const int e = g * EDIM + lane + j * 64;
            const float ph = red_hard[e] * (1.0f / 16384.0f);
            const float ps = red_soft[e] * (1.0f / 16384.0f);
            shh += ph * __logf(ph + 1e-7f);
            sss += ps * __logf(ps + 1e-7f);
        }
        #pragma unroll
        for (int off = 32; off > 0; off >>= 1) {
            shh += __shfl_xor(shh, off);
            sss += __shfl_xor(sss, off);
        }
        code += __expf(-shh);
        prob += __expf(-sss);
    }
    if (threadIdx.x == 0) {
        out[SCAL_OFF + 0] = code;
        out[SCAL_OFF + 1] = prob;
    }
}

extern "C" void kernel_launch(void* const* d_in, const int* in_sizes, int n_in,
                              void* d_out, int out_size, void* d_ws, size_t ws_size,
                              hipStream_t stream) {
    const float* x       = (const float*)d_in[0];
    const float* proj_w  = (const float*)d_in[1];
    const float* proj_b  = (const float*)d_in[2];
    const float* entries = (const float*)d_in[3];
    const float* gumbel  = (const float*)d_in[4];
    float* out = (float*)d_out;
    float* ws  = (float*)d_ws;
    float* logits = out + CB_OFF;
    ushort_t* Xb = (ushort_t*)(out + XB_OFF);
    ushort_t* Wb = (ushort_t*)(out + WB_OFF);

    float* red_hard = ws;            // 640 floats
    float* red_soft = ws + 640;      // 640 floats
    float* giyv     = ws + GIYV_OFF; // 65536 floats (32768 float2)
    float* slotS    = ws + SLOT_OFF;

    const size_t need1 = (size_t)(SLOT_OFF + SLOT_BIG_ROWS * 640) * 4;
    const int mode  = (ws_size >= need1) ? 1 : 0;
    const int nrows = (mode == 1) ? SLOT_BIG_ROWS : SLOT_SMALL_COPIES;
    // mode 1: slot rows fully overwritten -> zero only the 1280 reduction floats
    // mode 0: atomic copies must also be zeroed
    const int nz = (mode == 1) ? 1280 : (SLOT_OFF + SLOT_SMALL_COPIES * 640);
    const int redblocks = (640 * (nrows / 32) + 255) / 256;

    hipLaunchKernelGGL(vq_init_k, dim3((nz + 255) / 256), dim3(256), 0, stream,
                       ws, nz);
    hipLaunchKernelGGL(convert_bf16_k, dim3(4256), dim3(256), 0, stream,
                       x, proj_w, Xb, Wb);
    hipLaunchKernelGGL(gemm_mfma_k, dim3(NROWS / 128, GE / 128), dim3(256), 0, stream,
                       Xb, Wb, proj_b, logits);
    hipLaunchKernelGGL(vq_scan_k, dim3(4096), dim3(64), 0, stream,
                       logits, gumbel, red_hard, giyv, slotS, mode);
    hipLaunchKernelGGL(vq_emit_k, dim3(2048), dim3(256), 0, stream,
                       giyv, entries, logits, out);
    hipLaunchKernelGGL(reduce_soft3_k, dim3(redblocks), dim3(256), 0, stream,
                       slotS, nrows, red_soft);
    hipLaunchKernelGGL(vq_final_k, dim3(1), dim3(64), 0, stream,
                       red_hard, red_soft, out);
}

// Round 11
// 79.566 us; speedup vs baseline: 14.5151x; 1.3154x over previous
//
#include <hip/hip_runtime.h>
#include <hip/hip_bf16.h>

typedef unsigned short ushort_t;
typedef __attribute__((ext_vector_type(8))) short bf16x8;
typedef __attribute__((ext_vector_type(4))) float f32x4;

// Problem constants
#define NROWS 16384          // B*T
#define FDIM  512            // K
#define GE    640            // G*E
#define EDIM  320
#define DDIM  384
#define CB_OFF 12582912      // 16384*768
#define SCAL_OFF 23068672    // CB_OFF + 16384*640
// bf16 staging inside out[quantized region] (dead after gemm)
#define XB_OFF 0
#define WB_OFF 4194304

// ws layout (floats): [0,640) red_hard | [640,1280) red_soft | [1280,...) slots
#define SLOT_OFF 1280
#define SLOT_BIG_ROWS 1024   // plain-store path: 1024 rows x 640 floats = 2.6 MB
#define SLOT_SMALL_COPIES 64 // atomic fallback

// ---------------- init accumulators ----------------
__global__ void vq_init_k(float* acc, int n) {
    int i = blockIdx.x * 256 + threadIdx.x;
    if (i < n) acc[i] = 0.0f;
}

// ---------------- fp32 -> bf16 convert (RNE) ----------------
static __device__ __forceinline__ unsigned f2bf(float f) {
    unsigned u = __float_as_uint(f);
    return (u + 0x7FFFu + ((u >> 16) & 1u)) >> 16;
}

__global__ __launch_bounds__(256) void convert_bf16_k(
    const float* __restrict__ X, const float* __restrict__ W,
    ushort_t* __restrict__ Xb, ushort_t* __restrict__ Wb)
{
    const size_t i = (size_t)blockIdx.x * 256 + threadIdx.x;
    const float4* src;
    ushort_t* dst;
    if (i < 1048576) {
        src = (const float4*)X + i * 2;
        dst = Xb + i * 8;
    } else {
        const size_t j = i - 1048576;
        src = (const float4*)W + j * 2;
        dst = Wb + j * 8;
    }
    const float4 v0 = src[0], v1 = src[1];
    uint4 o;
    o.x = f2bf(v0.x) | (f2bf(v0.y) << 16);
    o.y = f2bf(v0.z) | (f2bf(v0.w) << 16);
    o.z = f2bf(v1.x) | (f2bf(v1.y) << 16);
    o.w = f2bf(v1.z) | (f2bf(v1.w) << 16);
    *(uint4*)dst = o;
}

// ---------------- async global->LDS helper ----------------
static __device__ __forceinline__ void gload16(const void* g, void* l) {
    __builtin_amdgcn_global_load_lds(
        (const __attribute__((address_space(1))) unsigned int*)g,
        (__attribute__((address_space(3))) unsigned int*)l, 16, 0, 0);
}

// ---------------- MFMA GEMM: L = Xb @ Wb^T + b ----------------
__global__ __launch_bounds__(256) void gemm_mfma_k(
    const ushort_t* __restrict__ Xb, const ushort_t* __restrict__ Wb,
    const float* __restrict__ bias, float* __restrict__ L)
{
    __shared__ __align__(16) ushort_t As[128 * 32];
    __shared__ __align__(16) ushort_t Bs[128 * 32];

    const int tid  = threadIdx.x;
    const int lane = tid & 63;
    const int wv   = tid >> 6;
    const int wr   = (wv >> 1) * 64;
    const int wc   = (wv & 1) * 64;
    const int row0 = blockIdx.x * 128;
    const int col0 = blockIdx.y * 128;

    const int c0r = tid >> 2;
    const int c0k = (tid & 3) * 8;

    f32x4 acc[4][4] = {};

    const int rA = lane & 15;
    const int kb = (lane >> 4) * 8;

    for (int t = 0; t < 16; ++t) {
        const int k0 = t * 32;
        gload16(Xb + (size_t)(row0 + c0r) * FDIM + k0 + c0k,        &As[tid * 8]);
        gload16(Xb + (size_t)(row0 + 64 + c0r) * FDIM + k0 + c0k,   &As[2048 + tid * 8]);
        gload16(Wb + (size_t)(col0 + c0r) * FDIM + k0 + c0k,        &Bs[tid * 8]);
        gload16(Wb + (size_t)(col0 + 64 + c0r) * FDIM + k0 + c0k,   &Bs[2048 + tid * 8]);
        __syncthreads();

        bf16x8 af[4], bfr[4];
        #pragma unroll
        for (int mi = 0; mi < 4; ++mi)
            af[mi] = *(const bf16x8*)&As[(wr + mi * 16 + rA) * 32 + kb];
        #pragma unroll
        for (int ni = 0; ni < 4; ++ni)
            bfr[ni] = *(const bf16x8*)&Bs[(wc + ni * 16 + rA) * 32 + kb];

        #pragma unroll
        for (int mi = 0; mi < 4; ++mi)
            #pragma unroll
            for (int ni = 0; ni < 4; ++ni)
                acc[mi][ni] = __builtin_amdgcn_mfma_f32_16x16x32_bf16(
                    af[mi], bfr[ni], acc[mi][ni], 0, 0, 0);
        __syncthreads();
    }

    const int colb = col0 + wc + (lane & 15);
    const int rowb = row0 + wr + (lane >> 4) * 4;
    #pragma unroll
    for (int ni = 0; ni < 4; ++ni) {
        const int col = colb + ni * 16;
        const float bv = bias[col];
        #pragma unroll
        for (int mi = 0; mi < 4; ++mi) {
            const int row = rowb + mi * 16;
            #pragma unroll
            for (int j = 0; j < 4; ++j)
                L[(size_t)(row + j) * GE + col] = acc[mi][ni][j] + bv;
        }
    }
}

// ---------------- FUSED scan + emit ----------------
// 1024 blocks x 256 threads (4 waves). Block owns 16 rows x both g = 32 units.
// Wave w handles units u = w*8 + (lane&7); u = g*16 + nr (g = u>>4, nr = u&15).
// Lane (r,o): o = lane>>3 owns elements e = s*32 + o*4 + k of its unit's row
//  -> per load instruction the wave reads 8 rows x contiguous 128B: coalesced,
//     no LDS staging (R10 lesson: 22KB LDS @ 64-thread blocks = 7 waves/CU).
// Emits cb one-hot + quantized via block-cooperative coalesced f4 stores.
// Soft partials -> plain slot-row stores; hard counts -> 32K direct atomics.
__global__ __launch_bounds__(256) void vq_fused_k(
    float* __restrict__ Lcb,                 // logits in, cb out (same region)
    const float* __restrict__ gumbel,
    const float* __restrict__ entries,
    float* __restrict__ qout,                // d_out base (quantized at 0)
    float* __restrict__ red_hard,            // ws[0..640)
    float* __restrict__ slotS,               // ws[SLOT_OFF..)
    int mode)                                // 1 = plain slots, 0 = atomic copies
{
    __shared__ float part[4][320];
    __shared__ float yv_a[32];
    __shared__ int   gi_a[32];

    const int tid  = threadIdx.x;
    const int lane = tid & 63;
    const int w    = tid >> 6;          // wave 0..3
    const int r    = lane & 7;
    const int o    = lane >> 3;
    const int u    = w * 8 + r;         // unit 0..31 == g*16 + nr
    const int g    = u >> 4;
    const int nr   = u & 15;
    const int n0   = blockIdx.x * 16;
    const int n    = n0 + nr;

    const float* lrow = Lcb + (size_t)n * GE + g * EDIM;
    const float* grow = gumbel + ((size_t)n * 2 + g) * EDIM;

    // ---- load own elements (e = s*32 + o*4 + k), coalesced f32x4 ----
    f32x4 l4[10], g4[10];
    #pragma unroll
    for (int s = 0; s < 10; ++s) {
        l4[s] = *(const f32x4*)(lrow + s * 32 + o * 4);
        g4[s] = *(const f32x4*)(grow + s * 32 + o * 4);
    }

    // ---- P1: max + argmax (per-lane e ascends with (s,k): first-index exact) ----
    float mh = -3.4e38f, mg = -3.4e38f;
    int hi = 0, gi = 0;
    #pragma unroll
    for (int s = 0; s < 10; ++s) {
        #pragma unroll
        for (int k = 0; k < 4; ++k) {
            const float lv = l4[s][k];
            const float tv = (lv + g4[s][k]) * 0.5f;   // (logits+gumbel)/TAU
            const int e = s * 32 + o * 4 + k;
            if (lv > mh) { mh = lv; hi = e; }
            if (tv > mg) { mg = tv; gi = e; }
        }
    }
    #pragma unroll
    for (int off = 8; off < 64; off <<= 1) {   // merge octants (same r)
        const float om = __shfl_xor(mh, off); const int oi = __shfl_xor(hi, off);
        if (om > mh || (om == mh && oi < hi)) { mh = om; hi = oi; }
        const float om2 = __shfl_xor(mg, off); const int oi2 = __shfl_xor(gi, off);
        if (om2 > mg || (om2 == mg && oi2 < gi)) { mg = om2; gi = oi2; }
    }

    // ---- P2: exps + sums ----
    f32x4 eh[10];
    float sh = 0.f, sg = 0.f;
    #pragma unroll
    for (int s = 0; s < 10; ++s) {
        f32x4 e4;
        #pragma unroll
        for (int k = 0; k < 4; ++k) {
            const float lv = l4[s][k];
            const float tv = (lv + g4[s][k]) * 0.5f;
            const float ev = __expf(lv - mh);
            e4[k] = ev;
            sh += ev;
            sg += __expf(tv - mg);
        }
        eh[s] = e4;
    }
    #pragma unroll
    for (int off = 8; off < 64; off <<= 1) {
        sh += __shfl_xor(sh, off);
        sg += __shfl_xor(sg, off);
    }
    const float ish = 1.0f / sh;
    const float isg = 1.0f / sg;                 // y_soft at its argmax == 1/sg
    const float yv  = (1.0f - isg) + isg;        // straight-through value

    // ---- publish per-unit scalars + hard-count atomic ----
    if (o == 0) {
        yv_a[u] = yv;
        gi_a[u] = gi;
        atomicAdd(&red_hard[g * EDIM + hi], 1.0f);
    }

    // ---- soft partials: merge rows (xor 1,2,4 across r), r==0 writes ----
    #pragma unroll
    for (int s = 0; s < 10; ++s) {
        f32x4 p4;
        #pragma unroll
        for (int k = 0; k < 4; ++k) p4[k] = eh[s][k] * ish;
        #pragma unroll
        for (int off = 1; off < 8; off <<= 1) {
            #pragma unroll
            for (int k = 0; k < 4; ++k) p4[k] += __shfl_xor(p4[k], off);
        }
        if (r == 0) *(f32x4*)&part[w][s * 32 + o * 4] = p4;
    }
    __syncthreads();

    // ---- emit cb: 16 rows x 640 = 2560 f4, coalesced ----
    #pragma unroll
    for (int it = 0; it < 10; ++it) {
        const int idx = it * 256 + tid;
        const int rr  = idx / 160;
        const int c4  = idx % 160;
        const int gg  = (c4 >= 80) ? 1 : 0;
        const int e4  = (c4 - gg * 80) * 4;
        const int uu  = gg * 16 + rr;
        const int gii = gi_a[uu];
        const float yvv = yv_a[uu];
        f32x4 cv;
        #pragma unroll
        for (int k = 0; k < 4; ++k) cv[k] = (e4 + k == gii) ? yvv : 0.0f;
        *(f32x4*)(Lcb + (size_t)(n0 + rr) * GE + c4 * 4) = cv;
    }

    // ---- emit quantized: 16 rows x 768 = 3072 f4, coalesced ----
    #pragma unroll
    for (int it = 0; it < 12; ++it) {
        const int idx = it * 256 + tid;
        const int rr  = idx / 192;
        const int c4  = idx % 192;
        const int gg  = (c4 >= 96) ? 1 : 0;
        const int d4  = (c4 - gg * 96) * 4;
        const int uu  = gg * 16 + rr;
        const int gii = gi_a[uu];
        const float yvv = yv_a[uu];
        const f32x4 ev = *(const f32x4*)(entries + ((size_t)(gg * EDIM + gii)) * DDIM + d4);
        f32x4 qv;
        #pragma unroll
        for (int k = 0; k < 4; ++k) qv[k] = yvv * ev[k];
        *(f32x4*)(qout + (size_t)(n0 + rr) * 768 + c4 * 4) = qv;
    }

    // ---- sink soft partials: one 640-float row per block ----
    for (int e = tid; e < 640; e += 256) {
        const int gg = e / 320, ee = e % 320;
        const float s = part[gg * 2][ee] + part[gg * 2 + 1][ee];
        if (mode == 1) {
            slotS[(size_t)blockIdx.x * 640 + e] = s;
        } else {
            atomicAdd(&slotS[(size_t)(blockIdx.x & (SLOT_SMALL_COPIES - 1)) * 640 + e], s);
        }
    }
}

// ---------------- slot reduction, parallel chunked ----------------
__global__ __launch_bounds__(256) void reduce_soft3_k(
    const float* __restrict__ slotS, int nrows, float* __restrict__ red_soft)
{
    const int gid = blockIdx.x * 256 + threadIdx.x;
    const int nchunk = nrows / 32;
    if (gid >= 640 * nchunk) return;
    const int col   = gid % 640;
    const int chunk = gid / 640;
    const int base  = chunk * 32;
    float a0 = 0.f, a1 = 0.f, a2 = 0.f, a3 = 0.f;
    #pragma unroll
    for (int k = 0; k < 32; k += 4) {
        a0 += slotS[(size_t)(base + k + 0) * 640 + col];
        a1 += slotS[(size_t)(base + k + 1) * 640 + col];
        a2 += slotS[(size_t)(base + k + 2) * 640 + col];
        a3 += slotS[(size_t)(base + k + 3) * 640 + col];
    }
    atomicAdd(&red_soft[col], (a0 + a1) + (a2 + a3));   // <=32 RMW per address
}

// ---------------- perplexities ----------------
__global__ void vq_final_k(const float* __restrict__ red_hard,
                           const float* __restrict__ red_soft,
                           float* __restrict__ out)
{
    const int lane = threadIdx.x & 63;
    float code = 0.f, prob = 0.f;
    for (int g = 0; g < 2; ++g) {
        float shh = 0.f, sss = 0.f;
        #pragma unroll
        for (int j = 0; j < 5; ++j) {
            const int e = g * EDIM + lane + j * 64;
            const float ph = red_hard[e] * (1.0f / 16384.0f);
            const float ps = red_soft[e] * (1.0f / 16384.0f);
            shh += ph * __logf(ph + 1e-7f);
            sss += ps * __logf(ps + 1e-7f);
        }
        #pragma unroll
        for (int off = 32; off > 0; off >>= 1) {
            shh += __shfl_xor(shh, off);
            sss += __shfl_xor(sss, off);
        }
        code += __expf(-shh);
        prob += __expf(-sss);
    }
    if (threadIdx.x == 0) {
        out[SCAL_OFF + 0] = code;
        out[SCAL_OFF + 1] = prob;
    }
}

extern "C" void kernel_launch(void* const* d_in, const int* in_sizes, int n_in,
                              void* d_out, int out_size, void* d_ws, size_t ws_size,
                              hipStream_t stream) {
    const float* x       = (const float*)d_in[0];
    const float* proj_w  = (const float*)d_in[1];
    const float* proj_b  = (const float*)d_in[2];
    const float* entries = (const float*)d_in[3];
    const float* gumbel  = (const float*)d_in[4];
    float* out = (float*)d_out;
    float* ws  = (float*)d_ws;
    float* logits = out + CB_OFF;
    ushort_t* Xb = (ushort_t*)(out + XB_OFF);
    ushort_t* Wb = (ushort_t*)(out + WB_OFF);

    float* red_hard = ws;            // 640 floats
    float* red_soft = ws + 640;      // 640 floats
    float* slotS    = ws + SLOT_OFF;

    const size_t need1 = (size_t)(SLOT_OFF + SLOT_BIG_ROWS * 640) * 4;
    const int mode  = (ws_size >= need1) ? 1 : 0;
    const int nrows = (mode == 1) ? SLOT_BIG_ROWS : SLOT_SMALL_COPIES;
    const int nz = (mode == 1) ? 1280 : (SLOT_OFF + SLOT_SMALL_COPIES * 640);
    const int redblocks = (640 * (nrows / 32) + 255) / 256;

    hipLaunchKernelGGL(vq_init_k, dim3((nz + 255) / 256), dim3(256), 0, stream,
                       ws, nz);
    hipLaunchKernelGGL(convert_bf16_k, dim3(4256), dim3(256), 0, stream,
                       x, proj_w, Xb, Wb);
    hipLaunchKernelGGL(gemm_mfma_k, dim3(NROWS / 128, GE / 128), dim3(256), 0, stream,
                       Xb, Wb, proj_b, logits);
    hipLaunchKernelGGL(vq_fused_k, dim3(1024), dim3(256), 0, stream,
                       logits, gumbel, entries, out, red_hard, slotS, mode);
    hipLaunchKernelGGL(reduce_soft3_k, dim3(redblocks), dim3(256), 0, stream,
                       slotS, nrows, red_soft);
    hipLaunchKernelGGL(vq_final_k, dim3(1), dim3(64), 0, stream,
                       red_hard, red_soft, out);
}

// Round 12
// 78.143 us; speedup vs baseline: 14.7795x; 1.0182x over previous
//
#include <hip/hip_runtime.h>
#include <hip/hip_bf16.h>

typedef unsigned short ushort_t;
typedef __attribute__((ext_vector_type(8))) short bf16x8;
typedef __attribute__((ext_vector_type(4))) float f32x4;

// Problem constants
#define NROWS 16384          // B*T
#define FDIM  512            // K
#define GE    640            // G*E
#define EDIM  320
#define DDIM  384
#define CB_OFF 12582912      // 16384*768
#define SCAL_OFF 23068672    // CB_OFF + 16384*640
// bf16 staging inside out[quantized region] (dead after gemm)
#define XB_OFF 0
#define WB_OFF 4194304

// ws layout (floats): [0,640) red_hard | [640,1280) red_soft | [1280,...) slots
#define SLOT_OFF 1280
#define SLOT_BIG_ROWS 2048   // plain-store path: 2048 rows x 640 floats = 5.2 MB
#define SLOT_SMALL_COPIES 64 // atomic fallback

// ---------------- init accumulators ----------------
__global__ void vq_init_k(float* acc, int n) {
    int i = blockIdx.x * 256 + threadIdx.x;
    if (i < n) acc[i] = 0.0f;
}

// ---------------- fp32 -> bf16 convert (RNE) ----------------
static __device__ __forceinline__ unsigned f2bf(float f) {
    unsigned u = __float_as_uint(f);
    return (u + 0x7FFFu + ((u >> 16) & 1u)) >> 16;
}

__global__ __launch_bounds__(256) void convert_bf16_k(
    const float* __restrict__ X, const float* __restrict__ W,
    ushort_t* __restrict__ Xb, ushort_t* __restrict__ Wb)
{
    const size_t i = (size_t)blockIdx.x * 256 + threadIdx.x;
    const float4* src;
    ushort_t* dst;
    if (i < 1048576) {
        src = (const float4*)X + i * 2;
        dst = Xb + i * 8;
    } else {
        const size_t j = i - 1048576;
        src = (const float4*)W + j * 2;
        dst = Wb + j * 8;
    }
    const float4 v0 = src[0], v1 = src[1];
    uint4 o;
    o.x = f2bf(v0.x) | (f2bf(v0.y) << 16);
    o.y = f2bf(v0.z) | (f2bf(v0.w) << 16);
    o.z = f2bf(v1.x) | (f2bf(v1.y) << 16);
    o.w = f2bf(v1.z) | (f2bf(v1.w) << 16);
    *(uint4*)dst = o;
}

// ---------------- async global->LDS helper ----------------
static __device__ __forceinline__ void gload16(const void* g, void* l) {
    __builtin_amdgcn_global_load_lds(
        (const __attribute__((address_space(1))) unsigned int*)g,
        (__attribute__((address_space(3))) unsigned int*)l, 16, 0, 0);
}

// ---------------- MFMA GEMM: L = Xb @ Wb^T + b ----------------
__global__ __launch_bounds__(256) void gemm_mfma_k(
    const ushort_t* __restrict__ Xb, const ushort_t* __restrict__ Wb,
    const float* __restrict__ bias, float* __restrict__ L)
{
    __shared__ __align__(16) ushort_t As[128 * 32];
    __shared__ __align__(16) ushort_t Bs[128 * 32];

    const int tid  = threadIdx.x;
    const int lane = tid & 63;
    const int wv   = tid >> 6;
    const int wr   = (wv >> 1) * 64;
    const int wc   = (wv & 1) * 64;
    const int row0 = blockIdx.x * 128;
    const int col0 = blockIdx.y * 128;

    const int c0r = tid >> 2;
    const int c0k = (tid & 3) * 8;

    f32x4 acc[4][4] = {};

    const int rA = lane & 15;
    const int kb = (lane >> 4) * 8;

    for (int t = 0; t < 16; ++t) {
        const int k0 = t * 32;
        gload16(Xb + (size_t)(row0 + c0r) * FDIM + k0 + c0k,        &As[tid * 8]);
        gload16(Xb + (size_t)(row0 + 64 + c0r) * FDIM + k0 + c0k,   &As[2048 + tid * 8]);
        gload16(Wb + (size_t)(col0 + c0r) * FDIM + k0 + c0k,        &Bs[tid * 8]);
        gload16(Wb + (size_t)(col0 + 64 + c0r) * FDIM + k0 + c0k,   &Bs[2048 + tid * 8]);
        __syncthreads();

        bf16x8 af[4], bfr[4];
        #pragma unroll
        for (int mi = 0; mi < 4; ++mi)
            af[mi] = *(const bf16x8*)&As[(wr + mi * 16 + rA) * 32 + kb];
        #pragma unroll
        for (int ni = 0; ni < 4; ++ni)
            bfr[ni] = *(const bf16x8*)&Bs[(wc + ni * 16 + rA) * 32 + kb];

        #pragma unroll
        for (int mi = 0; mi < 4; ++mi)
            #pragma unroll
            for (int ni = 0; ni < 4; ++ni)
                acc[mi][ni] = __builtin_amdgcn_mfma_f32_16x16x32_bf16(
                    af[mi], bfr[ni], acc[mi][ni], 0, 0, 0);
        __syncthreads();
    }

    const int colb = col0 + wc + (lane & 15);
    const int rowb = row0 + wr + (lane >> 4) * 4;
    #pragma unroll
    for (int ni = 0; ni < 4; ++ni) {
        const int col = colb + ni * 16;
        const float bv = bias[col];
        #pragma unroll
        for (int mi = 0; mi < 4; ++mi) {
            const int row = rowb + mi * 16;
            #pragma unroll
            for (int j = 0; j < 4; ++j)
                L[(size_t)(row + j) * GE + col] = acc[mi][ni][j] + bv;
        }
    }
}

// ---------------- FUSED scan + emit, high-occupancy ----------------
// 2048 blocks x 256 threads (4 waves). Block owns 8 rows x both g = 16 units.
// Wave w: units u = w*4 + (lane&3); u = g*8 + nr. Lane (r = lane&3, o = lane>>2)
// owns elements e = s*64 + o*4 + k (s<5, k<4) of its unit's row: per load
// instruction each of 4 rows contributes one contiguous 256B segment.
// No staging LDS; eh kept in regs. Emits cb + quantized block-cooperatively.
__global__ __launch_bounds__(256, 6) void vq_fused_k(
    float* __restrict__ Lcb,                 // logits in, cb out (same region)
    const float* __restrict__ gumbel,
    const float* __restrict__ entries,
    float* __restrict__ qout,                // d_out base (quantized at 0)
    float* __restrict__ red_hard,            // ws[0..640)
    float* __restrict__ slotS,               // ws[SLOT_OFF..)
    int mode)                                // 1 = plain slots, 0 = atomic copies
{
    __shared__ float part[4][320];
    __shared__ float yv_a[16];
    __shared__ int   gi_a[16];

    const int tid  = threadIdx.x;
    const int lane = tid & 63;
    const int w    = tid >> 6;          // wave 0..3
    const int r    = lane & 3;
    const int o    = lane >> 2;         // 0..15
    const int u    = w * 4 + r;         // unit 0..15 == g*8 + nr
    const int g    = u >> 3;
    const int nr   = u & 7;
    const int n0   = blockIdx.x * 8;
    const int n    = n0 + nr;

    const float* lrow = Lcb + (size_t)n * GE + g * EDIM;
    const float* grow = gumbel + ((size_t)n * 2 + g) * EDIM;

    // ---- load own elements (e = s*64 + o*4 + k), coalesced f32x4 ----
    f32x4 l4[5], g4[5];
    #pragma unroll
    for (int s = 0; s < 5; ++s) {
        l4[s] = *(const f32x4*)(lrow + s * 64 + o * 4);
        g4[s] = *(const f32x4*)(grow + s * 64 + o * 4);
    }

    // ---- P1: max + argmax (per-lane e ascends with (s,k): first-index exact) ----
    float mh = -3.4e38f, mg = -3.4e38f;
    int hi = 0, gi = 0;
    #pragma unroll
    for (int s = 0; s < 5; ++s) {
        #pragma unroll
        for (int k = 0; k < 4; ++k) {
            const float lv = l4[s][k];
            const float tv = (lv + g4[s][k]) * 0.5f;   // (logits+gumbel)/TAU
            const int e = s * 64 + o * 4 + k;
            if (lv > mh) { mh = lv; hi = e; }
            if (tv > mg) { mg = tv; gi = e; }
        }
    }
    #pragma unroll
    for (int off = 4; off < 64; off <<= 1) {   // merge o-lanes (same r)
        const float om = __shfl_xor(mh, off); const int oi = __shfl_xor(hi, off);
        if (om > mh || (om == mh && oi < hi)) { mh = om; hi = oi; }
        const float om2 = __shfl_xor(mg, off); const int oi2 = __shfl_xor(gi, off);
        if (om2 > mg || (om2 == mg && oi2 < gi)) { mg = om2; gi = oi2; }
    }

    // ---- P2: exps + sums ----
    f32x4 eh[5];
    float sh = 0.f, sg = 0.f;
    #pragma unroll
    for (int s = 0; s < 5; ++s) {
        f32x4 e4;
        #pragma unroll
        for (int k = 0; k < 4; ++k) {
            const float lv = l4[s][k];
            const float tv = (lv + g4[s][k]) * 0.5f;
            const float ev = __expf(lv - mh);
            e4[k] = ev;
            sh += ev;
            sg += __expf(tv - mg);
        }
        eh[s] = e4;
    }
    #pragma unroll
    for (int off = 4; off < 64; off <<= 1) {
        sh += __shfl_xor(sh, off);
        sg += __shfl_xor(sg, off);
    }
    const float ish = 1.0f / sh;
    const float isg = 1.0f / sg;                 // y_soft at its argmax == 1/sg
    const float yv  = (1.0f - isg) + isg;        // straight-through value

    // ---- publish per-unit scalars + hard-count atomic (16/block) ----
    if (o == 0) {
        yv_a[u] = yv;
        gi_a[u] = gi;
        atomicAdd(&red_hard[g * EDIM + hi], 1.0f);
    }

    // ---- soft partials: merge rows (xor 1,2 across r), r==0 writes ----
    #pragma unroll
    for (int s = 0; s < 5; ++s) {
        f32x4 p4;
        #pragma unroll
        for (int k = 0; k < 4; ++k) p4[k] = eh[s][k] * ish;
        #pragma unroll
        for (int off = 1; off < 4; off <<= 1) {
            #pragma unroll
            for (int k = 0; k < 4; ++k) p4[k] += __shfl_xor(p4[k], off);
        }
        if (r == 0) *(f32x4*)&part[w][s * 64 + o * 4] = p4;
    }
    __syncthreads();

    // ---- emit cb: 8 rows x 640 = 1280 f4, coalesced ----
    #pragma unroll
    for (int it = 0; it < 5; ++it) {
        const int idx = it * 256 + tid;
        const int rr  = idx / 160;
        const int c4  = idx % 160;
        const int gg  = (c4 >= 80) ? 1 : 0;
        const int e4  = (c4 - gg * 80) * 4;
        const int uu  = gg * 8 + rr;
        const int gii = gi_a[uu];
        const float yvv = yv_a[uu];
        f32x4 cv;
        #pragma unroll
        for (int k = 0; k < 4; ++k) cv[k] = (e4 + k == gii) ? yvv : 0.0f;
        *(f32x4*)(Lcb + (size_t)(n0 + rr) * GE + c4 * 4) = cv;
    }

    // ---- emit quantized: 8 rows x 768 = 1536 f4, coalesced ----
    #pragma unroll
    for (int it = 0; it < 6; ++it) {
        const int idx = it * 256 + tid;
        const int rr  = idx / 192;
        const int c4  = idx % 192;
        const int gg  = (c4 >= 96) ? 1 : 0;
        const int d4  = (c4 - gg * 96) * 4;
        const int uu  = gg * 8 + rr;
        const int gii = gi_a[uu];
        const float yvv = yv_a[uu];
        const f32x4 ev = *(const f32x4*)(entries + ((size_t)(gg * EDIM + gii)) * DDIM + d4);
        f32x4 qv;
        #pragma unroll
        for (int k = 0; k < 4; ++k) qv[k] = yvv * ev[k];
        *(f32x4*)(qout + (size_t)(n0 + rr) * 768 + c4 * 4) = qv;
    }

    // ---- sink soft partials: one 640-float row per block ----
    for (int e = tid; e < 640; e += 256) {
        const int gg = e / 320, ee = e % 320;
        const float s = part[gg * 2][ee] + part[gg * 2 + 1][ee];
        if (mode == 1) {
            slotS[(size_t)blockIdx.x * 640 + e] = s;
        } else {
            atomicAdd(&slotS[(size_t)(blockIdx.x & (SLOT_SMALL_COPIES - 1)) * 640 + e], s);
        }
    }
}

// ---------------- slot reduction, parallel chunked ----------------
__global__ __launch_bounds__(256) void reduce_soft3_k(
    const float* __restrict__ slotS, int nrows, float* __restrict__ red_soft)
{
    const int gid = blockIdx.x * 256 + threadIdx.x;
    const int nchunk = nrows / 32;
    if (gid >= 640 * nchunk) return;
    const int col   = gid % 640;
    const int chunk = gid / 640;
    const int base  = chunk * 32;
    float a0 = 0.f, a1 = 0.f, a2 = 0.f, a3 = 0.f;
    #pragma unroll
    for (int k = 0; k < 32; k += 4) {
        a0 += slotS[(size_t)(base + k + 0) * 640 + col];
        a1 += slotS[(size_t)(base + k + 1) * 640 + col];
        a2 += slotS[(size_t)(base + k + 2) * 640 + col];
        a3 += slotS[(size_t)(base + k + 3) * 640 + col];
    }
    atomicAdd(&red_soft[col], (a0 + a1) + (a2 + a3));   // <=64 RMW per address
}

// ---------------- perplexities ----------------
__global__ void vq_final_k(const float* __restrict__ red_hard,
                           const float* __restrict__ red_soft,
                           float* __restrict__ out)
{
    const int lane = threadIdx.x & 63;
    float code = 0.f, prob = 0.f;
    for (int g = 0; g < 2; ++g) {
        float shh = 0.f, sss = 0.f;
        #pragma unroll
        for (int j = 0; j < 5; ++j) {
            const int e = g * EDIM + lane + j * 64;
            const float ph = red_hard[e] * (1.0f / 16384.0f);
            const float ps = red_soft[e] * (1.0f / 16384.0f);
            shh += ph * __logf(ph + 1e-7f);
            sss += ps * __logf(ps + 1e-7f);
        }
        #pragma unroll
        for (int off = 32; off > 0; off >>= 1) {
            shh += __shfl_xor(shh, off);
            sss += __shfl_xor(sss, off);
        }
        code += __expf(-shh);
        prob += __expf(-sss);
    }
    if (threadIdx.x == 0) {
        out[SCAL_OFF + 0] = code;
        out[SCAL_OFF + 1] = prob;
    }
}

extern "C" void kernel_launch(void* const* d_in, const int* in_sizes, int n_in,
                              void* d_out, int out_size, void* d_ws, size_t ws_size,
                              hipStream_t stream) {
    const float* x       = (const float*)d_in[0];
    const float* proj_w  = (const float*)d_in[1];
    const float* proj_b  = (const float*)d_in[2];
    const float* entries = (const float*)d_in[3];
    const float* gumbel  = (const float*)d_in[4];
    float* out = (float*)d_out;
    float* ws  = (float*)d_ws;
    float* logits = out + CB_OFF;
    ushort_t* Xb = (ushort_t*)(out + XB_OFF);
    ushort_t* Wb = (ushort_t*)(out + WB_OFF);

    float* red_hard = ws;            // 640 floats
    float* red_soft = ws + 640;      // 640 floats
    float* slotS    = ws + SLOT_OFF;

    const size_t need1 = (size_t)(SLOT_OFF + SLOT_BIG_ROWS * 640) * 4;
    const int mode  = (ws_size >= need1) ? 1 : 0;
    const int nrows = (mode == 1) ? SLOT_BIG_ROWS : SLOT_SMALL_COPIES;
    const int nz = (mode == 1) ? 1280 : (SLOT_OFF + SLOT_SMALL_COPIES * 640);
    const int redblocks = (640 * (nrows / 32) + 255) / 256;

    hipLaunchKernelGGL(vq_init_k, dim3((nz + 255) / 256), dim3(256), 0, stream,
                       ws, nz);
    hipLaunchKernelGGL(convert_bf16_k, dim3(4256), dim3(256), 0, stream,
                       x, proj_w, Xb, Wb);
    hipLaunchKernelGGL(gemm_mfma_k, dim3(NROWS / 128, GE / 128), dim3(256), 0, stream,
                       Xb, Wb, proj_b, logits);
    hipLaunchKernelGGL(vq_fused_k, dim3(2048), dim3(256), 0, stream,
                       logits, gumbel, entries, out, red_hard, slotS, mode);
    hipLaunchKernelGGL(reduce_soft3_k, dim3(redblocks), dim3(256), 0, stream,
                       slotS, nrows, red_soft);
    hipLaunchKernelGGL(vq_final_k, dim3(1), dim3(64), 0, stream,
                       red_hard, red_soft, out);
}

// Round 13
// 75.868 us; speedup vs baseline: 15.2227x; 1.0300x over previous
//
#include <hip/hip_runtime.h>
#include <hip/hip_bf16.h>

typedef unsigned short ushort_t;
typedef __attribute__((ext_vector_type(8))) short bf16x8;
typedef __attribute__((ext_vector_type(4))) float f32x4;

// Problem constants
#define NROWS 16384          // B*T
#define FDIM  512            // K
#define GE    640            // G*E
#define EDIM  320
#define DDIM  384
#define CB_OFF 12582912      // 16384*768
#define SCAL_OFF 23068672    // CB_OFF + 16384*640
// bf16 staging inside out[quantized region] (dead after gemm)
#define XB_OFF 0
#define WB_OFF 4194304

// bf16 logits for row n are embedded in row n's own cb f32 span:
//   bytes [n*2560 + 1280, n*2560 + 2560) = (ushort*)(cb + n*640 + 320)
// The block that reads them is the block that overwrites them -> race-free.

// ws layout (floats): [0,640) red_hard | [640,1280) red_soft | [1280,...) slots
#define SLOT_OFF 1280
#define SLOT_BIG_ROWS 2048   // plain-store path: 2048 rows x 640 floats = 5.2 MB
#define SLOT_SMALL_COPIES 64 // atomic fallback

// ---------------- init accumulators ----------------
__global__ void vq_init_k(float* acc, int n) {
    int i = blockIdx.x * 256 + threadIdx.x;
    if (i < n) acc[i] = 0.0f;
}

// ---------------- fp32 -> bf16 convert (RNE) ----------------
static __device__ __forceinline__ unsigned f2bf(float f) {
    unsigned u = __float_as_uint(f);
    return (u + 0x7FFFu + ((u >> 16) & 1u)) >> 16;
}

__global__ __launch_bounds__(256) void convert_bf16_k(
    const float* __restrict__ X, const float* __restrict__ W,
    ushort_t* __restrict__ Xb, ushort_t* __restrict__ Wb)
{
    const size_t i = (size_t)blockIdx.x * 256 + threadIdx.x;
    const float4* src;
    ushort_t* dst;
    if (i < 1048576) {
        src = (const float4*)X + i * 2;
        dst = Xb + i * 8;
    } else {
        const size_t j = i - 1048576;
        src = (const float4*)W + j * 2;
        dst = Wb + j * 8;
    }
    const float4 v0 = src[0], v1 = src[1];
    uint4 o;
    o.x = f2bf(v0.x) | (f2bf(v0.y) << 16);
    o.y = f2bf(v0.z) | (f2bf(v0.w) << 16);
    o.z = f2bf(v1.x) | (f2bf(v1.y) << 16);
    o.w = f2bf(v1.z) | (f2bf(v1.w) << 16);
    *(uint4*)dst = o;
}

// ---------------- async global->LDS helper ----------------
static __device__ __forceinline__ void gload16(const void* g, void* l) {
    __builtin_amdgcn_global_load_lds(
        (const __attribute__((address_space(1))) unsigned int*)g,
        (__attribute__((address_space(3))) unsigned int*)l, 16, 0, 0);
}

// ---------------- MFMA GEMM: logits(bf16, embedded) = Xb @ Wb^T + b ----------------
__global__ __launch_bounds__(256) void gemm_mfma_k(
    const ushort_t* __restrict__ Xb, const ushort_t* __restrict__ Wb,
    const float* __restrict__ bias, float* __restrict__ L)   // L = cb region base
{
    __shared__ __align__(16) ushort_t As[128 * 32];
    __shared__ __align__(16) ushort_t Bs[128 * 32];

    const int tid  = threadIdx.x;
    const int lane = tid & 63;
    const int wv   = tid >> 6;
    const int wr   = (wv >> 1) * 64;
    const int wc   = (wv & 1) * 64;
    const int row0 = blockIdx.x * 128;
    const int col0 = blockIdx.y * 128;

    const int c0r = tid >> 2;
    const int c0k = (tid & 3) * 8;

    f32x4 acc[4][4] = {};

    const int rA = lane & 15;
    const int kb = (lane >> 4) * 8;

    for (int t = 0; t < 16; ++t) {
        const int k0 = t * 32;
        gload16(Xb + (size_t)(row0 + c0r) * FDIM + k0 + c0k,        &As[tid * 8]);
        gload16(Xb + (size_t)(row0 + 64 + c0r) * FDIM + k0 + c0k,   &As[2048 + tid * 8]);
        gload16(Wb + (size_t)(col0 + c0r) * FDIM + k0 + c0k,        &Bs[tid * 8]);
        gload16(Wb + (size_t)(col0 + 64 + c0r) * FDIM + k0 + c0k,   &Bs[2048 + tid * 8]);
        __syncthreads();

        bf16x8 af[4], bfr[4];
        #pragma unroll
        for (int mi = 0; mi < 4; ++mi)
            af[mi] = *(const bf16x8*)&As[(wr + mi * 16 + rA) * 32 + kb];
        #pragma unroll
        for (int ni = 0; ni < 4; ++ni)
            bfr[ni] = *(const bf16x8*)&Bs[(wc + ni * 16 + rA) * 32 + kb];

        #pragma unroll
        for (int mi = 0; mi < 4; ++mi)
            #pragma unroll
            for (int ni = 0; ni < 4; ++ni)
                acc[mi][ni] = __builtin_amdgcn_mfma_f32_16x16x32_bf16(
                    af[mi], bfr[ni], acc[mi][ni], 0, 0, 0);
        __syncthreads();
    }

    // C/D map: col = lane&15, row = (lane>>4)*4 + reg; store bf16 into the
    // upper half of each cb f32 row (embedded layout).
    const int colb = col0 + wc + (lane & 15);
    const int rowb = row0 + wr + (lane >> 4) * 4;
    #pragma unroll
    for (int ni = 0; ni < 4; ++ni) {
        const int col = colb + ni * 16;
        const float bv = bias[col];
        #pragma unroll
        for (int mi = 0; mi < 4; ++mi) {
            const int row = rowb + mi * 16;
            #pragma unroll
            for (int j = 0; j < 4; ++j) {
                ushort_t* lrow = (ushort_t*)(L + (size_t)(row + j) * GE + 320);
                lrow[col] = (ushort_t)f2bf(acc[mi][ni][j] + bv);
            }
        }
    }
}

// ---------------- FUSED scan + emit, bf16 logits ----------------
// 2048 blocks x 256 threads (4 waves). Block owns 8 rows x both g = 16 units.
// Wave w: units u = w*4 + (lane&3); u = g*8 + nr. Lane (r = lane&3, o = lane>>2)
// owns elements e = s*64 + o*4 + k (s<5, k<4) of its unit's row.
// Logits read as embedded bf16 (ushort4, coalesced 128B per row-group).
__global__ __launch_bounds__(256, 6) void vq_fused_k(
    float* __restrict__ Lcb,                 // cb region: bf16 logits in, f32 cb out
    const float* __restrict__ gumbel,
    const float* __restrict__ entries,
    float* __restrict__ qout,                // d_out base (quantized at 0)
    float* __restrict__ red_hard,            // ws[0..640)
    float* __restrict__ slotS,               // ws[SLOT_OFF..)
    int mode)                                // 1 = plain slots, 0 = atomic copies
{
    __shared__ float part[4][320];
    __shared__ float yv_a[16];
    __shared__ int   gi_a[16];

    const int tid  = threadIdx.x;
    const int lane = tid & 63;
    const int w    = tid >> 6;          // wave 0..3
    const int r    = lane & 3;
    const int o    = lane >> 2;         // 0..15
    const int u    = w * 4 + r;         // unit 0..15 == g*8 + nr
    const int g    = u >> 3;
    const int nr   = u & 7;
    const int n0   = blockIdx.x * 8;
    const int n    = n0 + nr;

    const ushort_t* lrow16 = (const ushort_t*)(Lcb + (size_t)n * GE + 320) + g * EDIM;
    const float* grow = gumbel + ((size_t)n * 2 + g) * EDIM;

    // ---- load own elements (e = s*64 + o*4 + k): bf16 logits + f32 gumbel ----
    f32x4 l4[5], g4[5];
    #pragma unroll
    for (int s = 0; s < 5; ++s) {
        const ushort4 lu = *(const ushort4*)(lrow16 + s * 64 + o * 4);
        l4[s][0] = __uint_as_float((unsigned)lu.x << 16);
        l4[s][1] = __uint_as_float((unsigned)lu.y << 16);
        l4[s][2] = __uint_as_float((unsigned)lu.z << 16);
        l4[s][3] = __uint_as_float((unsigned)lu.w << 16);
        g4[s] = *(const f32x4*)(grow + s * 64 + o * 4);
    }

    // ---- P1: max + argmax (first-index tie-break, exact on bf16 values) ----
    float mh = -3.4e38f, mg = -3.4e38f;
    int hi = 0, gi = 0;
    #pragma unroll
    for (int s = 0; s < 5; ++s) {
        #pragma unroll
        for (int k = 0; k < 4; ++k) {
            const float lv = l4[s][k];
            const float tv = (lv + g4[s][k]) * 0.5f;   // (logits+gumbel)/TAU
            const int e = s * 64 + o * 4 + k;
            if (lv > mh) { mh = lv; hi = e; }
            if (tv > mg) { mg = tv; gi = e; }
        }
    }
    #pragma unroll
    for (int off = 4; off < 64; off <<= 1) {   // merge o-lanes (same r)
        const float om = __shfl_xor(mh, off); const int oi = __shfl_xor(hi, off);
        if (om > mh || (om == mh && oi < hi)) { mh = om; hi = oi; }
        const float om2 = __shfl_xor(mg, off); const int oi2 = __shfl_xor(gi, off);
        if (om2 > mg || (om2 == mg && oi2 < gi)) { mg = om2; gi = oi2; }
    }

    // ---- P2: exps + sums ----
    f32x4 eh[5];
    float sh = 0.f, sg = 0.f;
    #pragma unroll
    for (int s = 0; s < 5; ++s) {
        f32x4 e4;
        #pragma unroll
        for (int k = 0; k < 4; ++k) {
            const float lv = l4[s][k];
            const float tv = (lv + g4[s][k]) * 0.5f;
            const float ev = __expf(lv - mh);
            e4[k] = ev;
            sh += ev;
            sg += __expf(tv - mg);
        }
        eh[s] = e4;
    }
    #pragma unroll
    for (int off = 4; off < 64; off <<= 1) {
        sh += __shfl_xor(sh, off);
        sg += __shfl_xor(sg, off);
    }
    const float ish = 1.0f / sh;
    const float isg = 1.0f / sg;                 // y_soft at its argmax == 1/sg
    const float yv  = (1.0f - isg) + isg;        // straight-through value

    // ---- publish per-unit scalars + hard-count atomic (16/block) ----
    if (o == 0) {
        yv_a[u] = yv;
        gi_a[u] = gi;
        atomicAdd(&red_hard[g * EDIM + hi], 1.0f);
    }

    // ---- soft partials: merge rows (xor 1,2 across r), r==0 writes ----
    #pragma unroll
    for (int s = 0; s < 5; ++s) {
        f32x4 p4;
        #pragma unroll
        for (int k = 0; k < 4; ++k) p4[k] = eh[s][k] * ish;
        #pragma unroll
        for (int off = 1; off < 4; off <<= 1) {
            #pragma unroll
            for (int k = 0; k < 4; ++k) p4[k] += __shfl_xor(p4[k], off);
        }
        if (r == 0) *(f32x4*)&part[w][s * 64 + o * 4] = p4;
    }
    __syncthreads();   // all waves done reading logits before cb overwrite

    // ---- emit cb: 8 rows x 640 = 1280 f4, coalesced (overwrites bf16 logits) ----
    #pragma unroll
    for (int it = 0; it < 5; ++it) {
        const int idx = it * 256 + tid;
        const int rr  = idx / 160;
        const int c4  = idx % 160;
        const int gg  = (c4 >= 80) ? 1 : 0;
        const int e4  = (c4 - gg * 80) * 4;
        const int uu  = gg * 8 + rr;
        const int gii = gi_a[uu];
        const float yvv = yv_a[uu];
        f32x4 cv;
        #pragma unroll
        for (int k = 0; k < 4; ++k) cv[k] = (e4 + k == gii) ? yvv : 0.0f;
        *(f32x4*)(Lcb + (size_t)(n0 + rr) * GE + c4 * 4) = cv;
    }

    // ---- emit quantized: 8 rows x 768 = 1536 f4, coalesced ----
    #pragma unroll
    for (int it = 0; it < 6; ++it) {
        const int idx = it * 256 + tid;
        const int rr  = idx / 192;
        const int c4  = idx % 192;
        const int gg  = (c4 >= 96) ? 1 : 0;
        const int d4  = (c4 - gg * 96) * 4;
        const int uu  = gg * 8 + rr;
        const int gii = gi_a[uu];
        const float yvv = yv_a[uu];
        const f32x4 ev = *(const f32x4*)(entries + ((size_t)(gg * EDIM + gii)) * DDIM + d4);
        f32x4 qv;
        #pragma unroll
        for (int k = 0; k < 4; ++k) qv[k] = yvv * ev[k];
        *(f32x4*)(qout + (size_t)(n0 + rr) * 768 + c4 * 4) = qv;
    }

    // ---- sink soft partials: one 640-float row per block ----
    for (int e = tid; e < 640; e += 256) {
        const int gg = e / 320, ee = e % 320;
        const float s = part[gg * 2][ee] + part[gg * 2 + 1][ee];
        if (mode == 1) {
            slotS[(size_t)blockIdx.x * 640 + e] = s;
        } else {
            atomicAdd(&slotS[(size_t)(blockIdx.x & (SLOT_SMALL_COPIES - 1)) * 640 + e], s);
        }
    }
}

// ---------------- slot reduction, parallel chunked ----------------
__global__ __launch_bounds__(256) void reduce_soft3_k(
    const float* __restrict__ slotS, int nrows, float* __restrict__ red_soft)
{
    const int gid = blockIdx.x * 256 + threadIdx.x;
    const int nchunk = nrows / 32;
    if (gid >= 640 * nchunk) return;
    const int col   = gid % 640;
    const int chunk = gid / 640;
    const int base  = chunk * 32;
    float a0 = 0.f, a1 = 0.f, a2 = 0.f, a3 = 0.f;
    #pragma unroll
    for (int k = 0; k < 32; k += 4) {
        a0 += slotS[(size_t)(base + k + 0) * 640 + col];
        a1 += slotS[(size_t)(base + k + 1) * 640 + col];
        a2 += slotS[(size_t)(base + k + 2) * 640 + col];
        a3 += slotS[(size_t)(base + k + 3) * 640 + col];
    }
    atomicAdd(&red_soft[col], (a0 + a1) + (a2 + a3));   // <=64 RMW per address
}

// ---------------- perplexities ----------------
__global__ void vq_final_k(const float* __restrict__ red_hard,
                           const float* __restrict__ red_soft,
                           float* __restrict__ out)
{
    const int lane = threadIdx.x & 63;
    float code = 0.f, prob = 0.f;
    for (int g = 0; g < 2; ++g) {
        float shh = 0.f, sss = 0.f;
        #pragma unroll
        for (int j = 0; j < 5; ++j) {
            const int e = g * EDIM + lane + j * 64;
            const float ph = red_hard[e] * (1.0f / 16384.0f);
            const float ps = red_soft[e] * (1.0f / 16384.0f);
            shh += ph * __logf(ph + 1e-7f);
            sss += ps * __logf(ps + 1e-7f);
        }
        #pragma unroll
        for (int off = 32; off > 0; off >>= 1) {
            shh += __shfl_xor(shh, off);
            sss += __shfl_xor(sss, off);
        }
        code += __expf(-shh);
        prob += __expf(-sss);
    }
    if (threadIdx.x == 0) {
        out[SCAL_OFF + 0] = code;
        out[SCAL_OFF + 1] = prob;
    }
}

extern "C" void kernel_launch(void* const* d_in, const int* in_sizes, int n_in,
                              void* d_out, int out_size, void* d_ws, size_t ws_size,
                              hipStream_t stream) {
    const float* x       = (const float*)d_in[0];
    const float* proj_w  = (const float*)d_in[1];
    const float* proj_b  = (const float*)d_in[2];
    const float* entries = (const float*)d_in[3];
    const float* gumbel  = (const float*)d_in[4];
    float* out = (float*)d_out;
    float* ws  = (float*)d_ws;
    float* cb = out + CB_OFF;                       // cb region (logits embedded)
    ushort_t* Xb = (ushort_t*)(out + XB_OFF);
    ushort_t* Wb = (ushort_t*)(out + WB_OFF);

    float* red_hard = ws;            // 640 floats
    float* red_soft = ws + 640;      // 640 floats
    float* slotS    = ws + SLOT_OFF;

    const size_t need1 = (size_t)(SLOT_OFF + SLOT_BIG_ROWS * 640) * 4;
    const int mode  = (ws_size >= need1) ? 1 : 0;
    const int nrows = (mode == 1) ? SLOT_BIG_ROWS : SLOT_SMALL_COPIES;
    const int nz = (mode == 1) ? 1280 : (SLOT_OFF + SLOT_SMALL_COPIES * 640);
    const int redblocks = (640 * (nrows / 32) + 255) / 256;

    hipLaunchKernelGGL(vq_init_k, dim3((nz + 255) / 256), dim3(256), 0, stream,
                       ws, nz);
    hipLaunchKernelGGL(convert_bf16_k, dim3(4256), dim3(256), 0, stream,
                       x, proj_w, Xb, Wb);
    hipLaunchKernelGGL(gemm_mfma_k, dim3(NROWS / 128, GE / 128), dim3(256), 0, stream,
                       Xb, Wb, proj_b, cb);
    hipLaunchKernelGGL(vq_fused_k, dim3(2048), dim3(256), 0, stream,
                       cb, gumbel, entries, out, red_hard, slotS, mode);
    hipLaunchKernelGGL(reduce_soft3_k, dim3(redblocks), dim3(256), 0, stream,
                       slotS, nrows, red_soft);
    hipLaunchKernelGGL(vq_final_k, dim3(1), dim3(64), 0, stream,
                       red_hard, red_soft, out);
}